// Round 1
// baseline (387.522 us; speedup 1.0000x reference)
//
#include <hip/hip_runtime.h>
#include <math.h>

#define DEVI static __device__ __forceinline__

typedef __attribute__((ext_vector_type(8))) short s16x8;
typedef __attribute__((ext_vector_type(4))) float f32x4;

DEVI float bf2f(unsigned short u) {
  union { unsigned int i; float f; } v; v.i = ((unsigned int)u) << 16; return v.f;
}
DEVI unsigned short f2bf(float f) {
  union { float f; unsigned int i; } v; v.f = f;
  return (unsigned short)((v.i + 0x7fffu + ((v.i >> 16) & 1u)) >> 16);
}

// ---------------- h0 = bf16(log1p(x)), vectorized ----------------
__global__ void log1p_cast_k(const float* __restrict__ x, unsigned short* __restrict__ h0, int n4) {
  int stride = gridDim.x * blockDim.x;
  for (int i = blockIdx.x * blockDim.x + threadIdx.x; i < n4; i += stride) {
    float4 v = ((const float4*)x)[i];
    ushort4 o;
    o.x = f2bf(log1pf(v.x)); o.y = f2bf(log1pf(v.y));
    o.z = f2bf(log1pf(v.z)); o.w = f2bf(log1pf(v.w));
    ((ushort4*)h0)[i] = o;
  }
}

// ---------------- weight prep: W[K][256] f32 -> Wt[256][K] bf16 ----------------
__global__ void prep_w_k(const float* __restrict__ Ws0, const float* __restrict__ Wn0,
                         const float* __restrict__ Ws1, const float* __restrict__ Wn1,
                         unsigned short* __restrict__ T0s, unsigned short* __restrict__ T0n,
                         unsigned short* __restrict__ T1s, unsigned short* __restrict__ T1n) {
  int i = blockIdx.x * 256 + threadIdx.x;
  if (i < 32768) {  // [256][128]
    int h = i >> 7, k = i & 127;
    T0s[i] = f2bf(Ws0[k * 256 + h]);
    T0n[i] = f2bf(Wn0[k * 256 + h]);
  }
  if (i < 65536) {  // [256][256]
    int h = i >> 8, k = i & 255;
    T1s[i] = f2bf(Ws1[k * 256 + h]);
    T1n[i] = f2bf(Wn1[k * 256 + h]);
  }
}

// ---------------- CSR build: count / scan / fill ----------------
__global__ void count_k(const int* __restrict__ dst, int E, unsigned* __restrict__ cnt) {
  int stride = gridDim.x * blockDim.x;
  for (int i = blockIdx.x * blockDim.x + threadIdx.x; i < E; i += stride)
    atomicAdd(&cnt[dst[i]], 1u);
}

__global__ void scan_block_sums_k(const unsigned* __restrict__ cnt, int M, unsigned* __restrict__ part) {
  __shared__ unsigned sm[256];
  int t = threadIdx.x;
  int i = blockIdx.x * 256 + t;
  sm[t] = (i < M) ? cnt[i] : 0u;
  __syncthreads();
  for (int o = 128; o > 0; o >>= 1) {
    if (t < o) sm[t] += sm[t + o];
    __syncthreads();
  }
  if (t == 0) part[blockIdx.x] = sm[0];
}

__global__ void scan_partials_k(unsigned* __restrict__ part, int P) {
  __shared__ unsigned sm[256];
  int t = threadIdx.x;
  unsigned v = (t < P) ? part[t] : 0u;
  sm[t] = v;
  __syncthreads();
  for (int o = 1; o < 256; o <<= 1) {
    unsigned xv = (t >= o) ? sm[t - o] : 0u;
    __syncthreads();
    sm[t] += xv;
    __syncthreads();
  }
  if (t < P) part[t] = sm[t] - v;  // exclusive
}

__global__ void scan_final_k(const unsigned* __restrict__ cnt, int M, const unsigned* __restrict__ part,
                             unsigned* __restrict__ off, unsigned* __restrict__ cur) {
  __shared__ unsigned sm[256];
  int t = threadIdx.x;
  int i = blockIdx.x * 256 + t;
  unsigned v = (i < M) ? cnt[i] : 0u;
  sm[t] = v;
  __syncthreads();
  for (int o = 1; o < 256; o <<= 1) {
    unsigned xv = (t >= o) ? sm[t - o] : 0u;
    __syncthreads();
    sm[t] += xv;
    __syncthreads();
  }
  if (i < M) {
    unsigned e = part[blockIdx.x] + sm[t] - v;
    off[i] = e;
    cur[i] = e;
  }
}

__global__ void fill_k(const int* __restrict__ src, const int* __restrict__ dst, int E,
                       unsigned* __restrict__ cur, int* __restrict__ ss) {
  int stride = gridDim.x * blockDim.x;
  for (int i = blockIdx.x * blockDim.x + threadIdx.x; i < E; i += stride) {
    int d = dst[i];
    unsigned p = atomicAdd(&cur[d], 1u);
    ss[p] = src[i];
  }
}

// ---------------- mean aggregation: wave per dst node ----------------
template <int FPL>  // feats per lane: F = FPL*64
__global__ __launch_bounds__(256) void aggregate_k(const unsigned short* __restrict__ hsrc,
                                                   const int* __restrict__ ss,
                                                   const unsigned* __restrict__ off,
                                                   const unsigned* __restrict__ cnt,
                                                   unsigned short* __restrict__ agg, int M) {
  const int F = FPL * 64;
  int w = threadIdx.x >> 6, l = threadIdx.x & 63;
  int d = blockIdx.x * 4 + w;
  if (d >= M) return;
  unsigned o = off[d];
  int n = (int)cnt[d];
  float acc[FPL];
#pragma unroll
  for (int f = 0; f < FPL; ++f) acc[f] = 0.f;
  for (int i = 0; i < n; ++i) {
    int s = ss[o + i];
    if constexpr (FPL == 2) {
      unsigned v = *(const unsigned*)&hsrc[(size_t)s * F + l * 2];
      acc[0] += bf2f((unsigned short)(v & 0xffffu));
      acc[1] += bf2f((unsigned short)(v >> 16));
    } else {
      ushort4 v = *(const ushort4*)&hsrc[(size_t)s * F + l * 4];
      acc[0] += bf2f(v.x); acc[1] += bf2f(v.y); acc[2] += bf2f(v.z); acc[3] += bf2f(v.w);
    }
  }
  float inv = 1.0f / (float)((n > 0) ? n : 1);
  if constexpr (FPL == 2) {
    unsigned ov = (unsigned)f2bf(acc[0] * inv) | ((unsigned)f2bf(acc[1] * inv) << 16);
    *(unsigned*)&agg[(size_t)d * F + l * 2] = ov;
  } else {
    ushort4 ov;
    ov.x = f2bf(acc[0] * inv); ov.y = f2bf(acc[1] * inv);
    ov.z = f2bf(acc[2] * inv); ov.w = f2bf(acc[3] * inv);
    *(ushort4*)&agg[(size_t)d * F + l * 4] = ov;
  }
}

// ---------------- fused layer GEMM: relu(Aself@Ws + Aagg@Wn + b) row-L2-normalized ----------------
// Tile: BM=64 rows x 256 cols, 4 waves; wave w owns cols [w*64, w*64+64).
template <int KD>
__global__ __launch_bounds__(256) void layer_gemm_k(const unsigned short* __restrict__ Aself,
                                                    const unsigned short* __restrict__ Aagg,
                                                    const unsigned short* __restrict__ WtS,
                                                    const unsigned short* __restrict__ WtN,
                                                    const float* __restrict__ bias,
                                                    unsigned short* __restrict__ Hout, int M) {
  __shared__ unsigned short At[64][40];   // pad 32->40: 2-way bank aliasing only
  __shared__ unsigned short Bt[256][40];
  __shared__ float rowsq[4][64];
  __shared__ float rowtot[64];

  int tid = threadIdx.x;
  int w = tid >> 6, l = tid & 63;
  int m0 = blockIdx.x * 64;

  f32x4 acc[4][4];
#pragma unroll
  for (int rt = 0; rt < 4; ++rt)
#pragma unroll
    for (int ct = 0; ct < 4; ++ct) acc[rt][ct] = (f32x4)(0.f);

  for (int s = 0; s < 2; ++s) {
    const unsigned short* A = s ? Aagg : Aself;
    const unsigned short* Wt = s ? WtN : WtS;
    for (int k0 = 0; k0 < KD; k0 += 32) {
      {  // stage A tile 64x32
        int r = tid >> 2, c8 = (tid & 3) << 3;
        int gr = m0 + r;
        uint4 v = make_uint4(0, 0, 0, 0);
        if (gr < M) v = *(const uint4*)&A[(size_t)gr * KD + k0 + c8];
        *(uint4*)&At[r][c8] = v;
      }
#pragma unroll
      for (int rr = 0; rr < 4; ++rr) {  // stage B tile: Wt rows 0..255, cols k0..k0+31
        int r = (tid >> 2) + (rr << 6), c8 = (tid & 3) << 3;
        uint4 v = *(const uint4*)&Wt[(size_t)r * KD + k0 + c8];
        *(uint4*)&Bt[r][c8] = v;
      }
      __syncthreads();
      s16x8 a[4], b[4];
#pragma unroll
      for (int rt = 0; rt < 4; ++rt) a[rt] = *(const s16x8*)&At[rt * 16 + (l & 15)][(l >> 4) * 8];
#pragma unroll
      for (int ct = 0; ct < 4; ++ct) b[ct] = *(const s16x8*)&Bt[w * 64 + ct * 16 + (l & 15)][(l >> 4) * 8];
#pragma unroll
      for (int rt = 0; rt < 4; ++rt)
#pragma unroll
        for (int ct = 0; ct < 4; ++ct)
          acc[rt][ct] = __builtin_amdgcn_mfma_f32_16x16x32_bf16(a[rt], b[ct], acc[rt][ct], 0, 0, 0);
      __syncthreads();
    }
  }

  // epilogue: bias + relu + partial row sumsq
  float pr[4][4];
#pragma unroll
  for (int rt = 0; rt < 4; ++rt)
#pragma unroll
    for (int j = 0; j < 4; ++j) pr[rt][j] = 0.f;
#pragma unroll
  for (int rt = 0; rt < 4; ++rt)
#pragma unroll
    for (int ct = 0; ct < 4; ++ct) {
      int c = w * 64 + ct * 16 + (l & 15);
      float bv = bias[c];
#pragma unroll
      for (int j = 0; j < 4; ++j) {
        float v = acc[rt][ct][j] + bv;
        v = fmaxf(v, 0.f);
        acc[rt][ct][j] = v;
        pr[rt][j] += v * v;
      }
    }
  // reduce across the 16 lanes sharing a row
#pragma unroll
  for (int rt = 0; rt < 4; ++rt)
#pragma unroll
    for (int j = 0; j < 4; ++j) {
      float p = pr[rt][j];
      for (int m = 1; m < 16; m <<= 1) p += __shfl_xor(p, m, 64);
      pr[rt][j] = p;
    }
  if ((l & 15) == 0) {
#pragma unroll
    for (int rt = 0; rt < 4; ++rt)
#pragma unroll
      for (int j = 0; j < 4; ++j) rowsq[w][rt * 16 + (l >> 4) * 4 + j] = pr[rt][j];
  }
  __syncthreads();
  if (tid < 64) rowtot[tid] = rowsq[0][tid] + rowsq[1][tid] + rowsq[2][tid] + rowsq[3][tid];
  __syncthreads();
#pragma unroll
  for (int rt = 0; rt < 4; ++rt) {
    int rbase = rt * 16 + (l >> 4) * 4;
#pragma unroll
    for (int j = 0; j < 4; ++j) {
      int r = rbase + j;
      int gr = m0 + r;
      if (gr < M) {
        float nrm = fmaxf(sqrtf(rowtot[r]), 1e-12f);
        float inv = 1.0f / nrm;
#pragma unroll
        for (int ct = 0; ct < 4; ++ct) {
          int c = w * 64 + ct * 16 + (l & 15);
          Hout[(size_t)gr * 256 + c] = f2bf(acc[rt][ct][j] * inv);
        }
      }
    }
  }
}

// ---------------- head: z_loc = h@Wmu+bmu ; z_scale = exp(h@Wvar+bvar)+1e-6 ----------------
__global__ __launch_bounds__(256) void head_k(const unsigned short* __restrict__ h2,
                                              const float* __restrict__ Wmu, const float* __restrict__ bmu,
                                              const float* __restrict__ Wvar, const float* __restrict__ bvar,
                                              float* __restrict__ out, int M) {
  int t = threadIdx.x;
  int j = t & 63;
  int r = blockIdx.x * 4 + (t >> 6);
  if (r >= M) return;
  bool mu = j < 32;
  const float* W = mu ? Wmu : Wvar;
  int c = j & 31;
  float acc = mu ? bmu[c] : bvar[c];
  const unsigned short* hr = &h2[(size_t)r * 256];
#pragma unroll 8
  for (int k = 0; k < 256; ++k) acc += bf2f(hr[k]) * W[k * 32 + c];
  if (mu)
    out[(size_t)r * 32 + c] = acc;
  else
    out[(size_t)M * 32 + (size_t)r * 32 + c] = expf(acc) + 1e-6f;
}

extern "C" void kernel_launch(void* const* d_in, const int* in_sizes, int n_in,
                              void* d_out, int out_size, void* d_ws, size_t ws_size,
                              hipStream_t stream) {
  const float* x    = (const float*)d_in[0];
  const float* Ws0  = (const float*)d_in[1];
  const float* Wn0  = (const float*)d_in[2];
  const float* b0   = (const float*)d_in[3];
  const float* Ws1  = (const float*)d_in[4];
  const float* Wn1  = (const float*)d_in[5];
  const float* b1   = (const float*)d_in[6];
  const float* Wmu  = (const float*)d_in[7];
  const float* bmu  = (const float*)d_in[8];
  const float* Wvar = (const float*)d_in[9];
  const float* bvar = (const float*)d_in[10];
  const int* src0   = (const int*)d_in[11];
  const int* dst0   = (const int*)d_in[12];
  const int* src1   = (const int*)d_in[13];
  const int* dst1   = (const int*)d_in[14];

  const int N0 = in_sizes[0] / 128;  // 200000
  const int E0 = in_sizes[11];       // 800000
  const int E1 = in_sizes[13];       // 160000
  const int N1 = 50000, N2 = 10000;  // n_dst0 / n_dst1 (fixed problem shape)

  char* ws = (char*)d_ws;
  size_t o = 0;
  auto take = [&](size_t b) -> char* {
    size_t cur = (o + 255) & ~(size_t)255;
    o = cur + b;
    return ws + cur;
  };
  unsigned short* h0   = (unsigned short*)take((size_t)N0 * 128 * 2);
  unsigned short* agg0 = (unsigned short*)take((size_t)N1 * 128 * 2);
  unsigned short* h1   = (unsigned short*)take((size_t)N1 * 256 * 2);
  unsigned short* agg1 = (unsigned short*)take((size_t)N2 * 256 * 2);
  unsigned short* h2   = (unsigned short*)take((size_t)N2 * 256 * 2);
  unsigned short* T0s  = (unsigned short*)take(256 * 128 * 2);
  unsigned short* T0n  = (unsigned short*)take(256 * 128 * 2);
  unsigned short* T1s  = (unsigned short*)take(256 * 256 * 2);
  unsigned short* T1n  = (unsigned short*)take(256 * 256 * 2);
  unsigned* cnt0 = (unsigned*)take((size_t)(N1 + N2) * 4);
  unsigned* cnt1 = cnt0 + N1;
  unsigned* off0 = (unsigned*)take((size_t)N1 * 4);
  unsigned* cur0 = (unsigned*)take((size_t)N1 * 4);
  unsigned* off1 = (unsigned*)take((size_t)N2 * 4);
  unsigned* cur1 = (unsigned*)take((size_t)N2 * 4);
  unsigned* part = (unsigned*)take(256 * 4);
  int* ss0 = (int*)take((size_t)E0 * 4);
  int* ss1 = (int*)take((size_t)E1 * 4);
  (void)ws_size;

  hipMemsetAsync(cnt0, 0, (size_t)(N1 + N2) * 4, stream);
  prep_w_k<<<256, 256, 0, stream>>>(Ws0, Wn0, Ws1, Wn1, T0s, T0n, T1s, T1n);
  log1p_cast_k<<<4096, 256, 0, stream>>>(x, h0, N0 * 128 / 4);

  // layer 0 CSR + aggregate + GEMM
  count_k<<<1024, 256, 0, stream>>>(dst0, E0, cnt0);
  int P0 = (N1 + 255) / 256;
  scan_block_sums_k<<<P0, 256, 0, stream>>>(cnt0, N1, part);
  scan_partials_k<<<1, 256, 0, stream>>>(part, P0);
  scan_final_k<<<P0, 256, 0, stream>>>(cnt0, N1, part, off0, cur0);
  fill_k<<<1024, 256, 0, stream>>>(src0, dst0, E0, cur0, ss0);
  aggregate_k<2><<<(N1 + 3) / 4, 256, 0, stream>>>(h0, ss0, off0, cnt0, agg0, N1);
  layer_gemm_k<128><<<(N1 + 63) / 64, 256, 0, stream>>>(h0, agg0, T0s, T0n, b0, h1, N1);

  // layer 1 CSR + aggregate + GEMM
  count_k<<<512, 256, 0, stream>>>(dst1, E1, cnt1);
  int P1 = (N2 + 255) / 256;
  scan_block_sums_k<<<P1, 256, 0, stream>>>(cnt1, N2, part);
  scan_partials_k<<<1, 256, 0, stream>>>(part, P1);
  scan_final_k<<<P1, 256, 0, stream>>>(cnt1, N2, part, off1, cur1);
  fill_k<<<512, 256, 0, stream>>>(src1, dst1, E1, cur1, ss1);
  aggregate_k<4><<<(N2 + 3) / 4, 256, 0, stream>>>(h1, ss1, off1, cnt1, agg1, N2);
  layer_gemm_k<256><<<(N2 + 63) / 64, 256, 0, stream>>>(h1, agg1, T1s, T1n, b1, h2, N2);

  head_k<<<(N2 + 3) / 4, 256, 0, stream>>>(h2, Wmu, bmu, Wvar, bvar, (float*)d_out, N2);
}

// Round 2
// 331.749 us; speedup vs baseline: 1.1681x; 1.1681x over previous
//
#include <hip/hip_runtime.h>
#include <math.h>

#define DEVI static __device__ __forceinline__

typedef __attribute__((ext_vector_type(8))) short s16x8;
typedef __attribute__((ext_vector_type(4))) float f32x4;

DEVI float bf2f(unsigned short u) {
  union { unsigned int i; float f; } v; v.i = ((unsigned int)u) << 16; return v.f;
}
DEVI unsigned short f2bf(float f) {
  union { float f; unsigned int i; } v; v.f = f;
  return (unsigned short)((v.i + 0x7fffu + ((v.i >> 16) & 1u)) >> 16);
}

// ---------------- h0 = bf16(log1p(x)), vectorized ----------------
__global__ void log1p_cast_k(const float* __restrict__ x, unsigned short* __restrict__ h0, int n4) {
  int stride = gridDim.x * blockDim.x;
  for (int i = blockIdx.x * blockDim.x + threadIdx.x; i < n4; i += stride) {
    float4 v = ((const float4*)x)[i];
    ushort4 o;
    o.x = f2bf(log1pf(v.x)); o.y = f2bf(log1pf(v.y));
    o.z = f2bf(log1pf(v.z)); o.w = f2bf(log1pf(v.w));
    ((ushort4*)h0)[i] = o;
  }
}

// ---------------- weight prep: W[K][256] f32 -> Wt[256][K] bf16 ----------------
__global__ void prep_w_k(const float* __restrict__ Ws0, const float* __restrict__ Wn0,
                         const float* __restrict__ Ws1, const float* __restrict__ Wn1,
                         unsigned short* __restrict__ T0s, unsigned short* __restrict__ T0n,
                         unsigned short* __restrict__ T1s, unsigned short* __restrict__ T1n) {
  int i = blockIdx.x * 256 + threadIdx.x;
  if (i < 32768) {  // [256][128]
    int h = i >> 7, k = i & 127;
    T0s[i] = f2bf(Ws0[k * 256 + h]);
    T0n[i] = f2bf(Wn0[k * 256 + h]);
  }
  if (i < 65536) {  // [256][256]
    int h = i >> 8, k = i & 255;
    T1s[i] = f2bf(Ws1[k * 256 + h]);
    T1n[i] = f2bf(Wn1[k * 256 + h]);
  }
}

// ---------------- CSR build: count / scan / fill ----------------
__global__ void count_k(const int* __restrict__ dst, int E, unsigned* __restrict__ cnt) {
  int stride = gridDim.x * blockDim.x;
  for (int i = blockIdx.x * blockDim.x + threadIdx.x; i < E; i += stride)
    atomicAdd(&cnt[dst[i]], 1u);
}

__global__ void scan_block_sums_k(const unsigned* __restrict__ cnt, int M, unsigned* __restrict__ part) {
  __shared__ unsigned sm[256];
  int t = threadIdx.x;
  int i = blockIdx.x * 256 + t;
  sm[t] = (i < M) ? cnt[i] : 0u;
  __syncthreads();
  for (int o = 128; o > 0; o >>= 1) {
    if (t < o) sm[t] += sm[t + o];
    __syncthreads();
  }
  if (t == 0) part[blockIdx.x] = sm[0];
}

__global__ void scan_partials_k(unsigned* __restrict__ part, int P) {
  __shared__ unsigned sm[256];
  int t = threadIdx.x;
  unsigned v = (t < P) ? part[t] : 0u;
  sm[t] = v;
  __syncthreads();
  for (int o = 1; o < 256; o <<= 1) {
    unsigned xv = (t >= o) ? sm[t - o] : 0u;
    __syncthreads();
    sm[t] += xv;
    __syncthreads();
  }
  if (t < P) part[t] = sm[t] - v;  // exclusive
}

__global__ void scan_final_k(const unsigned* __restrict__ cnt, int M, const unsigned* __restrict__ part,
                             unsigned* __restrict__ off, unsigned* __restrict__ cur) {
  __shared__ unsigned sm[256];
  int t = threadIdx.x;
  int i = blockIdx.x * 256 + t;
  unsigned v = (i < M) ? cnt[i] : 0u;
  sm[t] = v;
  __syncthreads();
  for (int o = 1; o < 256; o <<= 1) {
    unsigned xv = (t >= o) ? sm[t - o] : 0u;
    __syncthreads();
    sm[t] += xv;
    __syncthreads();
  }
  if (i < M) {
    unsigned e = part[blockIdx.x] + sm[t] - v;
    off[i] = e;
    cur[i] = e;
  }
}

__global__ void fill_k(const int* __restrict__ src, const int* __restrict__ dst, int E,
                       unsigned* __restrict__ cur, int* __restrict__ ss) {
  int stride = gridDim.x * blockDim.x;
  for (int i = blockIdx.x * blockDim.x + threadIdx.x; i < E; i += stride) {
    int d = dst[i];
    unsigned p = atomicAdd(&cur[d], 1u);
    ss[p] = src[i];
  }
}

// ---------------- mean aggregation: wave per dst node, 8-deep gather pipeline ----------------
// FPL = feats per lane (F = FPL*64). U = edges batched per issue group (MLP depth).
template <int FPL, int U>
__global__ __launch_bounds__(256) void aggregate_k(const unsigned short* __restrict__ hsrc,
                                                   const int* __restrict__ ss,
                                                   const unsigned* __restrict__ off,
                                                   const unsigned* __restrict__ cnt,
                                                   unsigned short* __restrict__ agg, int M) {
  const int F = FPL * 64;
  int w = threadIdx.x >> 6, l = threadIdx.x & 63;
  int d = blockIdx.x * 4 + w;
  if (d >= M) return;
  unsigned o = off[d];
  int n = (int)cnt[d];
  float acc[FPL];
#pragma unroll
  for (int f = 0; f < FPL; ++f) acc[f] = 0.f;

  int i = 0;
  for (; i + U <= n; i += U) {
    int sv[U];
#pragma unroll
    for (int u = 0; u < U; ++u) sv[u] = ss[o + i + u];
    if constexpr (FPL == 2) {
      unsigned v[U];
#pragma unroll
      for (int u = 0; u < U; ++u) v[u] = *(const unsigned*)&hsrc[(size_t)sv[u] * F + l * 2];
#pragma unroll
      for (int u = 0; u < U; ++u) {
        acc[0] += bf2f((unsigned short)(v[u] & 0xffffu));
        acc[1] += bf2f((unsigned short)(v[u] >> 16));
      }
    } else {
      uint2 v[U];
#pragma unroll
      for (int u = 0; u < U; ++u) v[u] = *(const uint2*)&hsrc[(size_t)sv[u] * F + l * 4];
#pragma unroll
      for (int u = 0; u < U; ++u) {
        acc[0] += bf2f((unsigned short)(v[u].x & 0xffffu));
        acc[1] += bf2f((unsigned short)(v[u].x >> 16));
        acc[2] += bf2f((unsigned short)(v[u].y & 0xffffu));
        acc[3] += bf2f((unsigned short)(v[u].y >> 16));
      }
    }
  }
  for (; i < n; ++i) {
    int s = ss[o + i];
    if constexpr (FPL == 2) {
      unsigned v = *(const unsigned*)&hsrc[(size_t)s * F + l * 2];
      acc[0] += bf2f((unsigned short)(v & 0xffffu));
      acc[1] += bf2f((unsigned short)(v >> 16));
    } else {
      uint2 v = *(const uint2*)&hsrc[(size_t)s * F + l * 4];
      acc[0] += bf2f((unsigned short)(v.x & 0xffffu));
      acc[1] += bf2f((unsigned short)(v.x >> 16));
      acc[2] += bf2f((unsigned short)(v.y & 0xffffu));
      acc[3] += bf2f((unsigned short)(v.y >> 16));
    }
  }

  float inv = 1.0f / (float)((n > 0) ? n : 1);
  if constexpr (FPL == 2) {
    unsigned ov = (unsigned)f2bf(acc[0] * inv) | ((unsigned)f2bf(acc[1] * inv) << 16);
    *(unsigned*)&agg[(size_t)d * F + l * 2] = ov;
  } else {
    ushort4 ov;
    ov.x = f2bf(acc[0] * inv); ov.y = f2bf(acc[1] * inv);
    ov.z = f2bf(acc[2] * inv); ov.w = f2bf(acc[3] * inv);
    *(ushort4*)&agg[(size_t)d * F + l * 4] = ov;
  }
}

// ---------------- fused layer GEMM: relu(Aself@Ws + Aagg@Wn + b) row-L2-normalized ----------------
// Tile: BM=64 rows x 256 cols, 4 waves; wave w owns cols [w*64, w*64+64).
template <int KD>
__global__ __launch_bounds__(256) void layer_gemm_k(const unsigned short* __restrict__ Aself,
                                                    const unsigned short* __restrict__ Aagg,
                                                    const unsigned short* __restrict__ WtS,
                                                    const unsigned short* __restrict__ WtN,
                                                    const float* __restrict__ bias,
                                                    unsigned short* __restrict__ Hout, int M) {
  __shared__ unsigned short At[64][40];   // pad 32->40: 2-way bank aliasing only
  __shared__ unsigned short Bt[256][40];
  __shared__ float rowsq[4][64];
  __shared__ float rowtot[64];

  int tid = threadIdx.x;
  int w = tid >> 6, l = tid & 63;
  int m0 = blockIdx.x * 64;

  f32x4 acc[4][4];
#pragma unroll
  for (int rt = 0; rt < 4; ++rt)
#pragma unroll
    for (int ct = 0; ct < 4; ++ct) acc[rt][ct] = (f32x4)(0.f);

  for (int s = 0; s < 2; ++s) {
    const unsigned short* A = s ? Aagg : Aself;
    const unsigned short* Wt = s ? WtN : WtS;
    for (int k0 = 0; k0 < KD; k0 += 32) {
      {  // stage A tile 64x32
        int r = tid >> 2, c8 = (tid & 3) << 3;
        int gr = m0 + r;
        uint4 v = make_uint4(0, 0, 0, 0);
        if (gr < M) v = *(const uint4*)&A[(size_t)gr * KD + k0 + c8];
        *(uint4*)&At[r][c8] = v;
      }
#pragma unroll
      for (int rr = 0; rr < 4; ++rr) {  // stage B tile: Wt rows 0..255, cols k0..k0+31
        int r = (tid >> 2) + (rr << 6), c8 = (tid & 3) << 3;
        uint4 v = *(const uint4*)&Wt[(size_t)r * KD + k0 + c8];
        *(uint4*)&Bt[r][c8] = v;
      }
      __syncthreads();
      s16x8 a[4], b[4];
#pragma unroll
      for (int rt = 0; rt < 4; ++rt) a[rt] = *(const s16x8*)&At[rt * 16 + (l & 15)][(l >> 4) * 8];
#pragma unroll
      for (int ct = 0; ct < 4; ++ct) b[ct] = *(const s16x8*)&Bt[w * 64 + ct * 16 + (l & 15)][(l >> 4) * 8];
#pragma unroll
      for (int rt = 0; rt < 4; ++rt)
#pragma unroll
        for (int ct = 0; ct < 4; ++ct)
          acc[rt][ct] = __builtin_amdgcn_mfma_f32_16x16x32_bf16(a[rt], b[ct], acc[rt][ct], 0, 0, 0);
      __syncthreads();
    }
  }

  // epilogue: bias + relu + partial row sumsq
  float pr[4][4];
#pragma unroll
  for (int rt = 0; rt < 4; ++rt)
#pragma unroll
    for (int j = 0; j < 4; ++j) pr[rt][j] = 0.f;
#pragma unroll
  for (int rt = 0; rt < 4; ++rt)
#pragma unroll
    for (int ct = 0; ct < 4; ++ct) {
      int c = w * 64 + ct * 16 + (l & 15);
      float bv = bias[c];
#pragma unroll
      for (int j = 0; j < 4; ++j) {
        float v = acc[rt][ct][j] + bv;
        v = fmaxf(v, 0.f);
        acc[rt][ct][j] = v;
        pr[rt][j] += v * v;
      }
    }
  // reduce across the 16 lanes sharing a row
#pragma unroll
  for (int rt = 0; rt < 4; ++rt)
#pragma unroll
    for (int j = 0; j < 4; ++j) {
      float p = pr[rt][j];
      for (int m = 1; m < 16; m <<= 1) p += __shfl_xor(p, m, 64);
      pr[rt][j] = p;
    }
  if ((l & 15) == 0) {
#pragma unroll
    for (int rt = 0; rt < 4; ++rt)
#pragma unroll
      for (int j = 0; j < 4; ++j) rowsq[w][rt * 16 + (l >> 4) * 4 + j] = pr[rt][j];
  }
  __syncthreads();
  if (tid < 64) rowtot[tid] = rowsq[0][tid] + rowsq[1][tid] + rowsq[2][tid] + rowsq[3][tid];
  __syncthreads();
#pragma unroll
  for (int rt = 0; rt < 4; ++rt) {
    int rbase = rt * 16 + (l >> 4) * 4;
#pragma unroll
    for (int j = 0; j < 4; ++j) {
      int r = rbase + j;
      int gr = m0 + r;
      if (gr < M) {
        float nrm = fmaxf(sqrtf(rowtot[r]), 1e-12f);
        float inv = 1.0f / nrm;
#pragma unroll
        for (int ct = 0; ct < 4; ++ct) {
          int c = w * 64 + ct * 16 + (l & 15);
          Hout[(size_t)gr * 256 + c] = f2bf(acc[rt][ct][j] * inv);
        }
      }
    }
  }
}

// ---------------- head: z_loc = h@Wmu+bmu ; z_scale = exp(h@Wvar+bvar)+1e-6 ----------------
__global__ __launch_bounds__(256) void head_k(const unsigned short* __restrict__ h2,
                                              const float* __restrict__ Wmu, const float* __restrict__ bmu,
                                              const float* __restrict__ Wvar, const float* __restrict__ bvar,
                                              float* __restrict__ out, int M) {
  int t = threadIdx.x;
  int j = t & 63;
  int r = blockIdx.x * 4 + (t >> 6);
  if (r >= M) return;
  bool mu = j < 32;
  const float* W = mu ? Wmu : Wvar;
  int c = j & 31;
  float acc = mu ? bmu[c] : bvar[c];
  const unsigned short* hr = &h2[(size_t)r * 256];
#pragma unroll 8
  for (int k = 0; k < 256; ++k) acc += bf2f(hr[k]) * W[k * 32 + c];
  if (mu)
    out[(size_t)r * 32 + c] = acc;
  else
    out[(size_t)M * 32 + (size_t)r * 32 + c] = expf(acc) + 1e-6f;
}

extern "C" void kernel_launch(void* const* d_in, const int* in_sizes, int n_in,
                              void* d_out, int out_size, void* d_ws, size_t ws_size,
                              hipStream_t stream) {
  const float* x    = (const float*)d_in[0];
  const float* Ws0  = (const float*)d_in[1];
  const float* Wn0  = (const float*)d_in[2];
  const float* b0   = (const float*)d_in[3];
  const float* Ws1  = (const float*)d_in[4];
  const float* Wn1  = (const float*)d_in[5];
  const float* b1   = (const float*)d_in[6];
  const float* Wmu  = (const float*)d_in[7];
  const float* bmu  = (const float*)d_in[8];
  const float* Wvar = (const float*)d_in[9];
  const float* bvar = (const float*)d_in[10];
  const int* src0   = (const int*)d_in[11];
  const int* dst0   = (const int*)d_in[12];
  const int* src1   = (const int*)d_in[13];
  const int* dst1   = (const int*)d_in[14];

  const int N0 = in_sizes[0] / 128;  // 200000
  const int E0 = in_sizes[11];       // 800000
  const int E1 = in_sizes[13];       // 160000
  const int N1 = 50000, N2 = 10000;  // n_dst0 / n_dst1 (fixed problem shape)

  char* ws = (char*)d_ws;
  size_t o = 0;
  auto take = [&](size_t b) -> char* {
    size_t cur = (o + 255) & ~(size_t)255;
    o = cur + b;
    return ws + cur;
  };
  unsigned short* h0   = (unsigned short*)take((size_t)N0 * 128 * 2);
  unsigned short* agg0 = (unsigned short*)take((size_t)N1 * 128 * 2);
  unsigned short* h1   = (unsigned short*)take((size_t)N1 * 256 * 2);
  unsigned short* agg1 = (unsigned short*)take((size_t)N2 * 256 * 2);
  unsigned short* h2   = (unsigned short*)take((size_t)N2 * 256 * 2);
  unsigned short* T0s  = (unsigned short*)take(256 * 128 * 2);
  unsigned short* T0n  = (unsigned short*)take(256 * 128 * 2);
  unsigned short* T1s  = (unsigned short*)take(256 * 256 * 2);
  unsigned short* T1n  = (unsigned short*)take(256 * 256 * 2);
  unsigned* cnt0 = (unsigned*)take((size_t)(N1 + N2) * 4);
  unsigned* cnt1 = cnt0 + N1;
  unsigned* off0 = (unsigned*)take((size_t)N1 * 4);
  unsigned* cur0 = (unsigned*)take((size_t)N1 * 4);
  unsigned* off1 = (unsigned*)take((size_t)N2 * 4);
  unsigned* cur1 = (unsigned*)take((size_t)N2 * 4);
  unsigned* part = (unsigned*)take(256 * 4);
  int* ss0 = (int*)take((size_t)E0 * 4);
  int* ss1 = (int*)take((size_t)E1 * 4);
  (void)ws_size;

  hipMemsetAsync(cnt0, 0, (size_t)(N1 + N2) * 4, stream);
  prep_w_k<<<256, 256, 0, stream>>>(Ws0, Wn0, Ws1, Wn1, T0s, T0n, T1s, T1n);
  log1p_cast_k<<<4096, 256, 0, stream>>>(x, h0, N0 * 128 / 4);

  // layer 0 CSR + aggregate + GEMM
  count_k<<<1024, 256, 0, stream>>>(dst0, E0, cnt0);
  int P0 = (N1 + 255) / 256;
  scan_block_sums_k<<<P0, 256, 0, stream>>>(cnt0, N1, part);
  scan_partials_k<<<1, 256, 0, stream>>>(part, P0);
  scan_final_k<<<P0, 256, 0, stream>>>(cnt0, N1, part, off0, cur0);
  fill_k<<<1024, 256, 0, stream>>>(src0, dst0, E0, cur0, ss0);
  aggregate_k<2, 8><<<(N1 + 3) / 4, 256, 0, stream>>>(h0, ss0, off0, cnt0, agg0, N1);
  layer_gemm_k<128><<<(N1 + 63) / 64, 256, 0, stream>>>(h0, agg0, T0s, T0n, b0, h1, N1);

  // layer 1 CSR + aggregate + GEMM
  count_k<<<512, 256, 0, stream>>>(dst1, E1, cnt1);
  int P1 = (N2 + 255) / 256;
  scan_block_sums_k<<<P1, 256, 0, stream>>>(cnt1, N2, part);
  scan_partials_k<<<1, 256, 0, stream>>>(part, P1);
  scan_final_k<<<P1, 256, 0, stream>>>(cnt1, N2, part, off1, cur1);
  fill_k<<<512, 256, 0, stream>>>(src1, dst1, E1, cur1, ss1);
  aggregate_k<4, 8><<<(N2 + 3) / 4, 256, 0, stream>>>(h1, ss1, off1, cnt1, agg1, N2);
  layer_gemm_k<256><<<(N2 + 63) / 64, 256, 0, stream>>>(h1, agg1, T1s, T1n, b1, h2, N2);

  head_k<<<(N2 + 3) / 4, 256, 0, stream>>>(h2, Wmu, bmu, Wvar, bvar, (float*)d_out, N2);
}

// Round 3
// 291.311 us; speedup vs baseline: 1.3303x; 1.1388x over previous
//
#include <hip/hip_runtime.h>
#include <math.h>

#define DEVI static __device__ __forceinline__

typedef __attribute__((ext_vector_type(8))) short s16x8;
typedef __attribute__((ext_vector_type(4))) float f32x4;

DEVI float bf2f(unsigned short u) {
  union { unsigned int i; float f; } v; v.i = ((unsigned int)u) << 16; return v.f;
}
DEVI unsigned short f2bf(float f) {
  union { float f; unsigned int i; } v; v.f = f;
  return (unsigned short)((v.i + 0x7fffu + ((v.i >> 16) & 1u)) >> 16);
}

// fast log1p for x in [0,1): 1+x in [1,2), no cancellation; hw log2 + scale.
DEVI float fast_log1p(float x) {
  float t = x + 1.0f;
  float l;
  asm("v_log_f32 %0, %1" : "=v"(l) : "v"(t));
  return l * 0.6931471805599453f;
}

// ---------------- h0 = bf16(log1p(x)), vectorized ----------------
__global__ void log1p_cast_k(const float* __restrict__ x, unsigned short* __restrict__ h0, int n4) {
  int stride = gridDim.x * blockDim.x;
  for (int i = blockIdx.x * blockDim.x + threadIdx.x; i < n4; i += stride) {
    float4 v = ((const float4*)x)[i];
    ushort4 o;
    o.x = f2bf(fast_log1p(v.x)); o.y = f2bf(fast_log1p(v.y));
    o.z = f2bf(fast_log1p(v.z)); o.w = f2bf(fast_log1p(v.w));
    ((ushort4*)h0)[i] = o;
  }
}

// ---------------- weight prep: W[K][256] f32 -> Wt[256][K] bf16 ----------------
__global__ void prep_w_k(const float* __restrict__ Ws0, const float* __restrict__ Wn0,
                         const float* __restrict__ Ws1, const float* __restrict__ Wn1,
                         unsigned short* __restrict__ T0s, unsigned short* __restrict__ T0n,
                         unsigned short* __restrict__ T1s, unsigned short* __restrict__ T1n) {
  int i = blockIdx.x * 256 + threadIdx.x;
  if (i < 32768) {  // [256][128]
    int h = i >> 7, k = i & 127;
    T0s[i] = f2bf(Ws0[k * 256 + h]);
    T0n[i] = f2bf(Wn0[k * 256 + h]);
  }
  if (i < 65536) {  // [256][256]
    int h = i >> 8, k = i & 255;
    T1s[i] = f2bf(Ws1[k * 256 + h]);
    T1n[i] = f2bf(Wn1[k * 256 + h]);
  }
}

// ---------------- CSR build: count / scan / fill ----------------
__global__ void count_k(const int* __restrict__ dst, int E, unsigned* __restrict__ cnt) {
  int stride = gridDim.x * blockDim.x;
  for (int i = blockIdx.x * blockDim.x + threadIdx.x; i < E; i += stride)
    atomicAdd(&cnt[dst[i]], 1u);
}

__global__ void scan_block_sums_k(const unsigned* __restrict__ cnt, int M, unsigned* __restrict__ part) {
  __shared__ unsigned sm[256];
  int t = threadIdx.x;
  int i = blockIdx.x * 256 + t;
  sm[t] = (i < M) ? cnt[i] : 0u;
  __syncthreads();
  for (int o = 128; o > 0; o >>= 1) {
    if (t < o) sm[t] += sm[t + o];
    __syncthreads();
  }
  if (t == 0) part[blockIdx.x] = sm[0];
}

__global__ void scan_partials_k(unsigned* __restrict__ part, int P) {
  __shared__ unsigned sm[256];
  int t = threadIdx.x;
  unsigned v = (t < P) ? part[t] : 0u;
  sm[t] = v;
  __syncthreads();
  for (int o = 1; o < 256; o <<= 1) {
    unsigned xv = (t >= o) ? sm[t - o] : 0u;
    __syncthreads();
    sm[t] += xv;
    __syncthreads();
  }
  if (t < P) part[t] = sm[t] - v;  // exclusive
}

__global__ void scan_final_k(const unsigned* __restrict__ cnt, int M, const unsigned* __restrict__ part,
                             unsigned* __restrict__ off, unsigned* __restrict__ cur) {
  __shared__ unsigned sm[256];
  int t = threadIdx.x;
  int i = blockIdx.x * 256 + t;
  unsigned v = (i < M) ? cnt[i] : 0u;
  sm[t] = v;
  __syncthreads();
  for (int o = 1; o < 256; o <<= 1) {
    unsigned xv = (t >= o) ? sm[t - o] : 0u;
    __syncthreads();
    sm[t] += xv;
    __syncthreads();
  }
  if (i < M) {
    unsigned e = part[blockIdx.x] + sm[t] - v;
    off[i] = e;
    cur[i] = e;
  }
}

__global__ void fill_k(const int* __restrict__ src, const int* __restrict__ dst, int E,
                       unsigned* __restrict__ cur, int* __restrict__ ss) {
  int stride = gridDim.x * blockDim.x;
  for (int i = blockIdx.x * blockDim.x + threadIdx.x; i < E; i += stride) {
    int d = dst[i];
    unsigned p = atomicAdd(&cur[d], 1u);
    ss[p] = src[i];
  }
}

// ---------------- mean aggregation: wave per dst node, 8-deep gather pipeline ----------------
// FPL = feats per lane (F = FPL*64). U = edges batched per issue group (MLP depth).
template <int FPL, int U>
__global__ __launch_bounds__(256) void aggregate_k(const unsigned short* __restrict__ hsrc,
                                                   const int* __restrict__ ss,
                                                   const unsigned* __restrict__ off,
                                                   const unsigned* __restrict__ cnt,
                                                   unsigned short* __restrict__ agg, int M) {
  const int F = FPL * 64;
  int w = threadIdx.x >> 6, l = threadIdx.x & 63;
  int d = blockIdx.x * 4 + w;
  if (d >= M) return;
  unsigned o = off[d];
  int n = (int)cnt[d];
  float acc[FPL];
#pragma unroll
  for (int f = 0; f < FPL; ++f) acc[f] = 0.f;

  int i = 0;
  for (; i + U <= n; i += U) {
    int sv[U];
#pragma unroll
    for (int u = 0; u < U; ++u) sv[u] = ss[o + i + u];
    if constexpr (FPL == 2) {
      unsigned v[U];
#pragma unroll
      for (int u = 0; u < U; ++u) v[u] = *(const unsigned*)&hsrc[(size_t)sv[u] * F + l * 2];
#pragma unroll
      for (int u = 0; u < U; ++u) {
        acc[0] += bf2f((unsigned short)(v[u] & 0xffffu));
        acc[1] += bf2f((unsigned short)(v[u] >> 16));
      }
    } else {
      uint2 v[U];
#pragma unroll
      for (int u = 0; u < U; ++u) v[u] = *(const uint2*)&hsrc[(size_t)sv[u] * F + l * 4];
#pragma unroll
      for (int u = 0; u < U; ++u) {
        acc[0] += bf2f((unsigned short)(v[u].x & 0xffffu));
        acc[1] += bf2f((unsigned short)(v[u].x >> 16));
        acc[2] += bf2f((unsigned short)(v[u].y & 0xffffu));
        acc[3] += bf2f((unsigned short)(v[u].y >> 16));
      }
    }
  }
  for (; i < n; ++i) {
    int s = ss[o + i];
    if constexpr (FPL == 2) {
      unsigned v = *(const unsigned*)&hsrc[(size_t)s * F + l * 2];
      acc[0] += bf2f((unsigned short)(v & 0xffffu));
      acc[1] += bf2f((unsigned short)(v >> 16));
    } else {
      uint2 v = *(const uint2*)&hsrc[(size_t)s * F + l * 4];
      acc[0] += bf2f((unsigned short)(v.x & 0xffffu));
      acc[1] += bf2f((unsigned short)(v.x >> 16));
      acc[2] += bf2f((unsigned short)(v.y & 0xffffu));
      acc[3] += bf2f((unsigned short)(v.y >> 16));
    }
  }

  float inv = 1.0f / (float)((n > 0) ? n : 1);
  if constexpr (FPL == 2) {
    unsigned ov = (unsigned)f2bf(acc[0] * inv) | ((unsigned)f2bf(acc[1] * inv) << 16);
    *(unsigned*)&agg[(size_t)d * F + l * 2] = ov;
  } else {
    ushort4 ov;
    ov.x = f2bf(acc[0] * inv); ov.y = f2bf(acc[1] * inv);
    ov.z = f2bf(acc[2] * inv); ov.w = f2bf(acc[3] * inv);
    *(ushort4*)&agg[(size_t)d * F + l * 4] = ov;
  }
}

// ---------------- fused layer GEMM: relu(Aself@Ws + Aagg@Wn + b) row-L2-normalized ----------------
// Tile: BM=64 rows x 256 cols, 4 waves; wave w owns cols [w*64, w*64+64).
template <int KD>
__global__ __launch_bounds__(256) void layer_gemm_k(const unsigned short* __restrict__ Aself,
                                                    const unsigned short* __restrict__ Aagg,
                                                    const unsigned short* __restrict__ WtS,
                                                    const unsigned short* __restrict__ WtN,
                                                    const float* __restrict__ bias,
                                                    unsigned short* __restrict__ Hout, int M) {
  __shared__ unsigned short At[64][40];   // pad 32->40: 2-way bank aliasing only
  __shared__ unsigned short Bt[256][40];
  __shared__ float rowsq[4][64];
  __shared__ float rowtot[64];

  int tid = threadIdx.x;
  int w = tid >> 6, l = tid & 63;
  int m0 = blockIdx.x * 64;

  f32x4 acc[4][4];
#pragma unroll
  for (int rt = 0; rt < 4; ++rt)
#pragma unroll
    for (int ct = 0; ct < 4; ++ct) acc[rt][ct] = (f32x4)(0.f);

  for (int s = 0; s < 2; ++s) {
    const unsigned short* A = s ? Aagg : Aself;
    const unsigned short* Wt = s ? WtN : WtS;
    for (int k0 = 0; k0 < KD; k0 += 32) {
      {  // stage A tile 64x32
        int r = tid >> 2, c8 = (tid & 3) << 3;
        int gr = m0 + r;
        uint4 v = make_uint4(0, 0, 0, 0);
        if (gr < M) v = *(const uint4*)&A[(size_t)gr * KD + k0 + c8];
        *(uint4*)&At[r][c8] = v;
      }
#pragma unroll
      for (int rr = 0; rr < 4; ++rr) {  // stage B tile: Wt rows 0..255, cols k0..k0+31
        int r = (tid >> 2) + (rr << 6), c8 = (tid & 3) << 3;
        uint4 v = *(const uint4*)&Wt[(size_t)r * KD + k0 + c8];
        *(uint4*)&Bt[r][c8] = v;
      }
      __syncthreads();
      s16x8 a[4], b[4];
#pragma unroll
      for (int rt = 0; rt < 4; ++rt) a[rt] = *(const s16x8*)&At[rt * 16 + (l & 15)][(l >> 4) * 8];
#pragma unroll
      for (int ct = 0; ct < 4; ++ct) b[ct] = *(const s16x8*)&Bt[w * 64 + ct * 16 + (l & 15)][(l >> 4) * 8];
#pragma unroll
      for (int rt = 0; rt < 4; ++rt)
#pragma unroll
        for (int ct = 0; ct < 4; ++ct)
          acc[rt][ct] = __builtin_amdgcn_mfma_f32_16x16x32_bf16(a[rt], b[ct], acc[rt][ct], 0, 0, 0);
      __syncthreads();
    }
  }

  // epilogue: bias + relu + partial row sumsq
  float pr[4][4];
#pragma unroll
  for (int rt = 0; rt < 4; ++rt)
#pragma unroll
    for (int j = 0; j < 4; ++j) pr[rt][j] = 0.f;
#pragma unroll
  for (int rt = 0; rt < 4; ++rt)
#pragma unroll
    for (int ct = 0; ct < 4; ++ct) {
      int c = w * 64 + ct * 16 + (l & 15);
      float bv = bias[c];
#pragma unroll
      for (int j = 0; j < 4; ++j) {
        float v = acc[rt][ct][j] + bv;
        v = fmaxf(v, 0.f);
        acc[rt][ct][j] = v;
        pr[rt][j] += v * v;
      }
    }
  // reduce across the 16 lanes sharing a row
#pragma unroll
  for (int rt = 0; rt < 4; ++rt)
#pragma unroll
    for (int j = 0; j < 4; ++j) {
      float p = pr[rt][j];
      for (int m = 1; m < 16; m <<= 1) p += __shfl_xor(p, m, 64);
      pr[rt][j] = p;
    }
  if ((l & 15) == 0) {
#pragma unroll
    for (int rt = 0; rt < 4; ++rt)
#pragma unroll
      for (int j = 0; j < 4; ++j) rowsq[w][rt * 16 + (l >> 4) * 4 + j] = pr[rt][j];
  }
  __syncthreads();
  if (tid < 64) rowtot[tid] = rowsq[0][tid] + rowsq[1][tid] + rowsq[2][tid] + rowsq[3][tid];
  __syncthreads();
#pragma unroll
  for (int rt = 0; rt < 4; ++rt) {
    int rbase = rt * 16 + (l >> 4) * 4;
#pragma unroll
    for (int j = 0; j < 4; ++j) {
      int r = rbase + j;
      int gr = m0 + r;
      if (gr < M) {
        float nrm = fmaxf(sqrtf(rowtot[r]), 1e-12f);
        float inv = 1.0f / nrm;
#pragma unroll
        for (int ct = 0; ct < 4; ++ct) {
          int c = w * 64 + ct * 16 + (l & 15);
          Hout[(size_t)gr * 256 + c] = f2bf(acc[rt][ct][j] * inv);
        }
      }
    }
  }
}

// ---------------- head: z_loc = h@Wmu+bmu ; z_scale = exp(h@Wvar+bvar)+1e-6 ----------------
__global__ __launch_bounds__(256) void head_k(const unsigned short* __restrict__ h2,
                                              const float* __restrict__ Wmu, const float* __restrict__ bmu,
                                              const float* __restrict__ Wvar, const float* __restrict__ bvar,
                                              float* __restrict__ out, int M) {
  int t = threadIdx.x;
  int j = t & 63;
  int r = blockIdx.x * 4 + (t >> 6);
  if (r >= M) return;
  bool mu = j < 32;
  const float* W = mu ? Wmu : Wvar;
  int c = j & 31;
  float acc = mu ? bmu[c] : bvar[c];
  const unsigned short* hr = &h2[(size_t)r * 256];
#pragma unroll 8
  for (int k = 0; k < 256; ++k) acc += bf2f(hr[k]) * W[k * 32 + c];
  if (mu)
    out[(size_t)r * 32 + c] = acc;
  else
    out[(size_t)M * 32 + (size_t)r * 32 + c] = expf(acc) + 1e-6f;
}

extern "C" void kernel_launch(void* const* d_in, const int* in_sizes, int n_in,
                              void* d_out, int out_size, void* d_ws, size_t ws_size,
                              hipStream_t stream) {
  const float* x    = (const float*)d_in[0];
  const float* Ws0  = (const float*)d_in[1];
  const float* Wn0  = (const float*)d_in[2];
  const float* b0   = (const float*)d_in[3];
  const float* Ws1  = (const float*)d_in[4];
  const float* Wn1  = (const float*)d_in[5];
  const float* b1   = (const float*)d_in[6];
  const float* Wmu  = (const float*)d_in[7];
  const float* bmu  = (const float*)d_in[8];
  const float* Wvar = (const float*)d_in[9];
  const float* bvar = (const float*)d_in[10];
  const int* src0   = (const int*)d_in[11];
  const int* dst0   = (const int*)d_in[12];
  const int* src1   = (const int*)d_in[13];
  const int* dst1   = (const int*)d_in[14];

  const int N0 = in_sizes[0] / 128;  // 200000
  const int E0 = in_sizes[11];       // 800000
  const int E1 = in_sizes[13];       // 160000
  const int N1 = 50000, N2 = 10000;  // n_dst0 / n_dst1 (fixed problem shape)

  char* ws = (char*)d_ws;
  size_t o = 0;
  auto take = [&](size_t b) -> char* {
    size_t cur = (o + 255) & ~(size_t)255;
    o = cur + b;
    return ws + cur;
  };
  unsigned short* h0   = (unsigned short*)take((size_t)N0 * 128 * 2);
  unsigned short* agg0 = (unsigned short*)take((size_t)N1 * 128 * 2);
  unsigned short* h1   = (unsigned short*)take((size_t)N1 * 256 * 2);
  unsigned short* agg1 = (unsigned short*)take((size_t)N2 * 256 * 2);
  unsigned short* h2   = (unsigned short*)take((size_t)N2 * 256 * 2);
  unsigned short* T0s  = (unsigned short*)take(256 * 128 * 2);
  unsigned short* T0n  = (unsigned short*)take(256 * 128 * 2);
  unsigned short* T1s  = (unsigned short*)take(256 * 256 * 2);
  unsigned short* T1n  = (unsigned short*)take(256 * 256 * 2);
  unsigned* cnt0 = (unsigned*)take((size_t)(N1 + N2) * 4);
  unsigned* cnt1 = cnt0 + N1;
  unsigned* off0 = (unsigned*)take((size_t)N1 * 4);
  unsigned* cur0 = (unsigned*)take((size_t)N1 * 4);
  unsigned* off1 = (unsigned*)take((size_t)N2 * 4);
  unsigned* cur1 = (unsigned*)take((size_t)N2 * 4);
  unsigned* part = (unsigned*)take(256 * 4);
  int* ss0 = (int*)take((size_t)E0 * 4);
  int* ss1 = (int*)take((size_t)E1 * 4);
  (void)ws_size;

  hipMemsetAsync(cnt0, 0, (size_t)(N1 + N2) * 4, stream);
  prep_w_k<<<256, 256, 0, stream>>>(Ws0, Wn0, Ws1, Wn1, T0s, T0n, T1s, T1n);
  log1p_cast_k<<<4096, 256, 0, stream>>>(x, h0, N0 * 128 / 4);

  // layer 0 CSR + aggregate + GEMM
  count_k<<<1024, 256, 0, stream>>>(dst0, E0, cnt0);
  int P0 = (N1 + 255) / 256;
  scan_block_sums_k<<<P0, 256, 0, stream>>>(cnt0, N1, part);
  scan_partials_k<<<1, 256, 0, stream>>>(part, P0);
  scan_final_k<<<P0, 256, 0, stream>>>(cnt0, N1, part, off0, cur0);
  fill_k<<<1024, 256, 0, stream>>>(src0, dst0, E0, cur0, ss0);
  aggregate_k<2, 8><<<(N1 + 3) / 4, 256, 0, stream>>>(h0, ss0, off0, cnt0, agg0, N1);
  layer_gemm_k<128><<<(N1 + 63) / 64, 256, 0, stream>>>(h0, agg0, T0s, T0n, b0, h1, N1);

  // layer 1 CSR + aggregate + GEMM
  count_k<<<512, 256, 0, stream>>>(dst1, E1, cnt1);
  int P1 = (N2 + 255) / 256;
  scan_block_sums_k<<<P1, 256, 0, stream>>>(cnt1, N2, part);
  scan_partials_k<<<1, 256, 0, stream>>>(part, P1);
  scan_final_k<<<P1, 256, 0, stream>>>(cnt1, N2, part, off1, cur1);
  fill_k<<<512, 256, 0, stream>>>(src1, dst1, E1, cur1, ss1);
  aggregate_k<4, 8><<<(N2 + 3) / 4, 256, 0, stream>>>(h1, ss1, off1, cnt1, agg1, N2);
  layer_gemm_k<256><<<(N2 + 63) / 64, 256, 0, stream>>>(h1, agg1, T1s, T1n, b1, h2, N2);

  head_k<<<(N2 + 3) / 4, 256, 0, stream>>>(h2, Wmu, bmu, Wvar, bvar, (float*)d_out, N2);
}

// Round 4
// 279.072 us; speedup vs baseline: 1.3886x; 1.0439x over previous
//
#include <hip/hip_runtime.h>
#include <math.h>

#define DEVI static __device__ __forceinline__

typedef __attribute__((ext_vector_type(8))) short s16x8;
typedef __attribute__((ext_vector_type(4))) float f32x4;

DEVI float bf2f(unsigned short u) {
  union { unsigned int i; float f; } v; v.i = ((unsigned int)u) << 16; return v.f;
}
DEVI unsigned short f2bf(float f) {
  union { float f; unsigned int i; } v; v.f = f;
  return (unsigned short)((v.i + 0x7fffu + ((v.i >> 16) & 1u)) >> 16);
}

// fast log1p for x in [0,1): 1+x in [1,2), no cancellation; hw log2 + scale.
DEVI float fast_log1p(float x) {
  float t = x + 1.0f;
  float l;
  asm("v_log_f32 %0, %1" : "=v"(l) : "v"(t));
  return l * 0.6931471805599453f;
}

// ---------------- h0 = bf16(log1p(x)), vectorized ----------------
__global__ void log1p_cast_k(const float* __restrict__ x, unsigned short* __restrict__ h0, int n4) {
  int stride = gridDim.x * blockDim.x;
  for (int i = blockIdx.x * blockDim.x + threadIdx.x; i < n4; i += stride) {
    float4 v = ((const float4*)x)[i];
    ushort4 o;
    o.x = f2bf(fast_log1p(v.x)); o.y = f2bf(fast_log1p(v.y));
    o.z = f2bf(fast_log1p(v.z)); o.w = f2bf(fast_log1p(v.w));
    ((ushort4*)h0)[i] = o;
  }
}

// ---------------- weight prep: W[K][256] f32 -> Wt[256][K] bf16 ----------------
__global__ void prep_w_k(const float* __restrict__ Ws0, const float* __restrict__ Wn0,
                         const float* __restrict__ Ws1, const float* __restrict__ Wn1,
                         unsigned short* __restrict__ T0s, unsigned short* __restrict__ T0n,
                         unsigned short* __restrict__ T1s, unsigned short* __restrict__ T1n) {
  int i = blockIdx.x * 256 + threadIdx.x;
  if (i < 32768) {  // [256][128]
    int h = i >> 7, k = i & 127;
    T0s[i] = f2bf(Ws0[k * 256 + h]);
    T0n[i] = f2bf(Wn0[k * 256 + h]);
  }
  if (i < 65536) {  // [256][256]
    int h = i >> 8, k = i & 255;
    T1s[i] = f2bf(Ws1[k * 256 + h]);
    T1n[i] = f2bf(Wn1[k * 256 + h]);
  }
}

// ---------------- CSR build (both layers fused): count / scan / fill ----------------
// Blocks [0,B0) process edge list 0 into cnt[0..N1); blocks [B0,..) list 1 into cnt[N1..N1+N2).
__global__ __launch_bounds__(256) void count2_k(const int* __restrict__ dst0, int E0,
                                                const int* __restrict__ dst1, int E1,
                                                unsigned* __restrict__ cnt, int N1, int B0) {
  int b = blockIdx.x;
  const int* dst; int E; unsigned* c; int base;
  if (b < B0) { dst = dst0; E = E0; c = cnt; base = b; }
  else        { dst = dst1; E = E1; c = cnt + N1; base = b - B0; }
  int i4 = (base * 256 + threadIdx.x) * 4;
  if (i4 + 3 < E) {
    int4 d = *(const int4*)&dst[i4];
    atomicAdd(&c[d.x], 1u); atomicAdd(&c[d.y], 1u);
    atomicAdd(&c[d.z], 1u); atomicAdd(&c[d.w], 1u);
  } else {
    for (int i = i4; i < E; ++i) atomicAdd(&c[dst[i]], 1u);
  }
}

__global__ void scan_block_sums_k(const unsigned* __restrict__ cnt, int M, unsigned* __restrict__ part) {
  __shared__ unsigned sm[256];
  int t = threadIdx.x;
  int i = blockIdx.x * 256 + t;
  sm[t] = (i < M) ? cnt[i] : 0u;
  __syncthreads();
  for (int o = 128; o > 0; o >>= 1) {
    if (t < o) sm[t] += sm[t + o];
    __syncthreads();
  }
  if (t == 0) part[blockIdx.x] = sm[0];
}

__global__ void scan_partials_k(unsigned* __restrict__ part, int P) {
  __shared__ unsigned sm[256];
  int t = threadIdx.x;
  unsigned v = (t < P) ? part[t] : 0u;
  sm[t] = v;
  __syncthreads();
  for (int o = 1; o < 256; o <<= 1) {
    unsigned xv = (t >= o) ? sm[t - o] : 0u;
    __syncthreads();
    sm[t] += xv;
    __syncthreads();
  }
  if (t < P) part[t] = sm[t] - v;  // exclusive
}

__global__ void scan_final_k(const unsigned* __restrict__ cnt, int M, const unsigned* __restrict__ part,
                             unsigned* __restrict__ off, unsigned* __restrict__ cur) {
  __shared__ unsigned sm[256];
  int t = threadIdx.x;
  int i = blockIdx.x * 256 + t;
  unsigned v = (i < M) ? cnt[i] : 0u;
  sm[t] = v;
  __syncthreads();
  for (int o = 1; o < 256; o <<= 1) {
    unsigned xv = (t >= o) ? sm[t - o] : 0u;
    __syncthreads();
    sm[t] += xv;
    __syncthreads();
  }
  if (i < M) {
    unsigned e = part[blockIdx.x] + sm[t] - v;
    off[i] = e;
    cur[i] = e;
  }
}

// 4 edges/thread: 1 int4 load each of dst/src, 4 independent atomics, 4 stores.
__global__ __launch_bounds__(256) void fill2_k(const int* __restrict__ src0, const int* __restrict__ dst0, int E0,
                                               const int* __restrict__ src1, const int* __restrict__ dst1, int E1,
                                               unsigned* __restrict__ cur, int N1, int B0,
                                               int* __restrict__ ss) {
  int b = blockIdx.x;
  const int* src; const int* dst; int E; unsigned* c; int base;
  if (b < B0) { src = src0; dst = dst0; E = E0; c = cur; base = b; }
  else        { src = src1; dst = dst1; E = E1; c = cur + N1; base = b - B0; }
  int i4 = (base * 256 + threadIdx.x) * 4;
  if (i4 + 3 < E) {
    int4 d = *(const int4*)&dst[i4];
    int4 s = *(const int4*)&src[i4];
    unsigned p0 = atomicAdd(&c[d.x], 1u);
    unsigned p1 = atomicAdd(&c[d.y], 1u);
    unsigned p2 = atomicAdd(&c[d.z], 1u);
    unsigned p3 = atomicAdd(&c[d.w], 1u);
    ss[p0] = s.x; ss[p1] = s.y; ss[p2] = s.z; ss[p3] = s.w;
  } else {
    for (int i = i4; i < E; ++i) {
      unsigned p = atomicAdd(&c[dst[i]], 1u);
      ss[p] = src[i];
    }
  }
}

// ---------------- mean aggregation: wave per dst node, U-deep gather pipeline ----------------
// FPL = feats per lane (F = FPL*64). off/cnt hold ABSOLUTE offsets into the shared ss buffer.
template <int FPL, int U>
__global__ __launch_bounds__(256) void aggregate_k(const unsigned short* __restrict__ hsrc,
                                                   const int* __restrict__ ss,
                                                   const unsigned* __restrict__ off,
                                                   const unsigned* __restrict__ cnt,
                                                   unsigned short* __restrict__ agg, int M) {
  const int F = FPL * 64;
  int w = threadIdx.x >> 6, l = threadIdx.x & 63;
  int d = blockIdx.x * 4 + w;
  if (d >= M) return;
  unsigned o = off[d];
  int n = (int)cnt[d];
  float acc[FPL];
#pragma unroll
  for (int f = 0; f < FPL; ++f) acc[f] = 0.f;

  int i = 0;
  for (; i + U <= n; i += U) {
    int sv[U];
#pragma unroll
    for (int u = 0; u < U; ++u) sv[u] = ss[o + i + u];
    if constexpr (FPL == 2) {
      unsigned v[U];
#pragma unroll
      for (int u = 0; u < U; ++u) v[u] = *(const unsigned*)&hsrc[(size_t)sv[u] * F + l * 2];
#pragma unroll
      for (int u = 0; u < U; ++u) {
        acc[0] += bf2f((unsigned short)(v[u] & 0xffffu));
        acc[1] += bf2f((unsigned short)(v[u] >> 16));
      }
    } else {
      uint2 v[U];
#pragma unroll
      for (int u = 0; u < U; ++u) v[u] = *(const uint2*)&hsrc[(size_t)sv[u] * F + l * 4];
#pragma unroll
      for (int u = 0; u < U; ++u) {
        acc[0] += bf2f((unsigned short)(v[u].x & 0xffffu));
        acc[1] += bf2f((unsigned short)(v[u].x >> 16));
        acc[2] += bf2f((unsigned short)(v[u].y & 0xffffu));
        acc[3] += bf2f((unsigned short)(v[u].y >> 16));
      }
    }
  }
  for (; i < n; ++i) {
    int s = ss[o + i];
    if constexpr (FPL == 2) {
      unsigned v = *(const unsigned*)&hsrc[(size_t)s * F + l * 2];
      acc[0] += bf2f((unsigned short)(v & 0xffffu));
      acc[1] += bf2f((unsigned short)(v >> 16));
    } else {
      uint2 v = *(const uint2*)&hsrc[(size_t)s * F + l * 4];
      acc[0] += bf2f((unsigned short)(v.x & 0xffffu));
      acc[1] += bf2f((unsigned short)(v.x >> 16));
      acc[2] += bf2f((unsigned short)(v.y & 0xffffu));
      acc[3] += bf2f((unsigned short)(v.y >> 16));
    }
  }

  float inv = 1.0f / (float)((n > 0) ? n : 1);
  if constexpr (FPL == 2) {
    unsigned ov = (unsigned)f2bf(acc[0] * inv) | ((unsigned)f2bf(acc[1] * inv) << 16);
    *(unsigned*)&agg[(size_t)d * F + l * 2] = ov;
  } else {
    ushort4 ov;
    ov.x = f2bf(acc[0] * inv); ov.y = f2bf(acc[1] * inv);
    ov.z = f2bf(acc[2] * inv); ov.w = f2bf(acc[3] * inv);
    *(ushort4*)&agg[(size_t)d * F + l * 4] = ov;
  }
}

// ---------------- fused layer GEMM: relu(Aself@Ws + Aagg@Wn + b) row-L2-normalized ----------------
// Tile: BM=64 rows x 256 cols, 4 waves; wave w owns cols [w*64, w*64+64).
template <int KD>
__global__ __launch_bounds__(256) void layer_gemm_k(const unsigned short* __restrict__ Aself,
                                                    const unsigned short* __restrict__ Aagg,
                                                    const unsigned short* __restrict__ WtS,
                                                    const unsigned short* __restrict__ WtN,
                                                    const float* __restrict__ bias,
                                                    unsigned short* __restrict__ Hout, int M) {
  __shared__ unsigned short At[64][40];   // pad 32->40: 2-way bank aliasing only
  __shared__ unsigned short Bt[256][40];
  __shared__ float rowsq[4][64];
  __shared__ float rowtot[64];

  int tid = threadIdx.x;
  int w = tid >> 6, l = tid & 63;
  int m0 = blockIdx.x * 64;

  f32x4 acc[4][4];
#pragma unroll
  for (int rt = 0; rt < 4; ++rt)
#pragma unroll
    for (int ct = 0; ct < 4; ++ct) acc[rt][ct] = (f32x4)(0.f);

  for (int s = 0; s < 2; ++s) {
    const unsigned short* A = s ? Aagg : Aself;
    const unsigned short* Wt = s ? WtN : WtS;
    for (int k0 = 0; k0 < KD; k0 += 32) {
      {  // stage A tile 64x32
        int r = tid >> 2, c8 = (tid & 3) << 3;
        int gr = m0 + r;
        uint4 v = make_uint4(0, 0, 0, 0);
        if (gr < M) v = *(const uint4*)&A[(size_t)gr * KD + k0 + c8];
        *(uint4*)&At[r][c8] = v;
      }
#pragma unroll
      for (int rr = 0; rr < 4; ++rr) {  // stage B tile: Wt rows 0..255, cols k0..k0+31
        int r = (tid >> 2) + (rr << 6), c8 = (tid & 3) << 3;
        uint4 v = *(const uint4*)&Wt[(size_t)r * KD + k0 + c8];
        *(uint4*)&Bt[r][c8] = v;
      }
      __syncthreads();
      s16x8 a[4], b[4];
#pragma unroll
      for (int rt = 0; rt < 4; ++rt) a[rt] = *(const s16x8*)&At[rt * 16 + (l & 15)][(l >> 4) * 8];
#pragma unroll
      for (int ct = 0; ct < 4; ++ct) b[ct] = *(const s16x8*)&Bt[w * 64 + ct * 16 + (l & 15)][(l >> 4) * 8];
#pragma unroll
      for (int rt = 0; rt < 4; ++rt)
#pragma unroll
        for (int ct = 0; ct < 4; ++ct)
          acc[rt][ct] = __builtin_amdgcn_mfma_f32_16x16x32_bf16(a[rt], b[ct], acc[rt][ct], 0, 0, 0);
      __syncthreads();
    }
  }

  // epilogue: bias + relu + partial row sumsq
  float pr[4][4];
#pragma unroll
  for (int rt = 0; rt < 4; ++rt)
#pragma unroll
    for (int j = 0; j < 4; ++j) pr[rt][j] = 0.f;
#pragma unroll
  for (int rt = 0; rt < 4; ++rt)
#pragma unroll
    for (int ct = 0; ct < 4; ++ct) {
      int c = w * 64 + ct * 16 + (l & 15);
      float bv = bias[c];
#pragma unroll
      for (int j = 0; j < 4; ++j) {
        float v = acc[rt][ct][j] + bv;
        v = fmaxf(v, 0.f);
        acc[rt][ct][j] = v;
        pr[rt][j] += v * v;
      }
    }
  // reduce across the 16 lanes sharing a row
#pragma unroll
  for (int rt = 0; rt < 4; ++rt)
#pragma unroll
    for (int j = 0; j < 4; ++j) {
      float p = pr[rt][j];
      for (int m = 1; m < 16; m <<= 1) p += __shfl_xor(p, m, 64);
      pr[rt][j] = p;
    }
  if ((l & 15) == 0) {
#pragma unroll
    for (int rt = 0; rt < 4; ++rt)
#pragma unroll
      for (int j = 0; j < 4; ++j) rowsq[w][rt * 16 + (l >> 4) * 4 + j] = pr[rt][j];
  }
  __syncthreads();
  if (tid < 64) rowtot[tid] = rowsq[0][tid] + rowsq[1][tid] + rowsq[2][tid] + rowsq[3][tid];
  __syncthreads();
#pragma unroll
  for (int rt = 0; rt < 4; ++rt) {
    int rbase = rt * 16 + (l >> 4) * 4;
#pragma unroll
    for (int j = 0; j < 4; ++j) {
      int r = rbase + j;
      int gr = m0 + r;
      if (gr < M) {
        float nrm = fmaxf(sqrtf(rowtot[r]), 1e-12f);
        float inv = 1.0f / nrm;
#pragma unroll
        for (int ct = 0; ct < 4; ++ct) {
          int c = w * 64 + ct * 16 + (l & 15);
          Hout[(size_t)gr * 256 + c] = f2bf(acc[rt][ct][j] * inv);
        }
      }
    }
  }
}

// ---------------- head: z_loc = h@Wmu+bmu ; z_scale = exp(h@Wvar+bvar)+1e-6 ----------------
__global__ __launch_bounds__(256) void head_k(const unsigned short* __restrict__ h2,
                                              const float* __restrict__ Wmu, const float* __restrict__ bmu,
                                              const float* __restrict__ Wvar, const float* __restrict__ bvar,
                                              float* __restrict__ out, int M) {
  int t = threadIdx.x;
  int j = t & 63;
  int r = blockIdx.x * 4 + (t >> 6);
  if (r >= M) return;
  bool mu = j < 32;
  const float* W = mu ? Wmu : Wvar;
  int c = j & 31;
  float acc = mu ? bmu[c] : bvar[c];
  const unsigned short* hr = &h2[(size_t)r * 256];
#pragma unroll 8
  for (int k = 0; k < 256; ++k) acc += bf2f(hr[k]) * W[k * 32 + c];
  if (mu)
    out[(size_t)r * 32 + c] = acc;
  else
    out[(size_t)M * 32 + (size_t)r * 32 + c] = expf(acc) + 1e-6f;
}

extern "C" void kernel_launch(void* const* d_in, const int* in_sizes, int n_in,
                              void* d_out, int out_size, void* d_ws, size_t ws_size,
                              hipStream_t stream) {
  const float* x    = (const float*)d_in[0];
  const float* Ws0  = (const float*)d_in[1];
  const float* Wn0  = (const float*)d_in[2];
  const float* b0   = (const float*)d_in[3];
  const float* Ws1  = (const float*)d_in[4];
  const float* Wn1  = (const float*)d_in[5];
  const float* b1   = (const float*)d_in[6];
  const float* Wmu  = (const float*)d_in[7];
  const float* bmu  = (const float*)d_in[8];
  const float* Wvar = (const float*)d_in[9];
  const float* bvar = (const float*)d_in[10];
  const int* src0   = (const int*)d_in[11];
  const int* dst0   = (const int*)d_in[12];
  const int* src1   = (const int*)d_in[13];
  const int* dst1   = (const int*)d_in[14];

  const int N0 = in_sizes[0] / 128;  // 200000
  const int E0 = in_sizes[11];       // 800000
  const int E1 = in_sizes[13];       // 160000
  const int N1 = 50000, N2 = 10000;  // n_dst0 / n_dst1 (fixed problem shape)
  const int M = N1 + N2;

  char* ws = (char*)d_ws;
  size_t o = 0;
  auto take = [&](size_t b) -> char* {
    size_t cur = (o + 255) & ~(size_t)255;
    o = cur + b;
    return ws + cur;
  };
  unsigned short* h0   = (unsigned short*)take((size_t)N0 * 128 * 2);
  unsigned short* agg0 = (unsigned short*)take((size_t)N1 * 128 * 2);
  unsigned short* h1   = (unsigned short*)take((size_t)N1 * 256 * 2);
  unsigned short* agg1 = (unsigned short*)take((size_t)N2 * 256 * 2);
  unsigned short* h2   = (unsigned short*)take((size_t)N2 * 256 * 2);
  unsigned short* T0s  = (unsigned short*)take(256 * 128 * 2);
  unsigned short* T0n  = (unsigned short*)take(256 * 128 * 2);
  unsigned short* T1s  = (unsigned short*)take(256 * 256 * 2);
  unsigned short* T1n  = (unsigned short*)take(256 * 256 * 2);
  unsigned* cnt  = (unsigned*)take((size_t)M * 4);   // cnt0 | cnt1
  unsigned* off  = (unsigned*)take((size_t)M * 4);   // absolute offsets into ss
  unsigned* cur  = (unsigned*)take((size_t)M * 4);
  unsigned* part = (unsigned*)take(256 * 4);
  int* ss = (int*)take((size_t)(E0 + E1) * 4);       // shared edge-src buffer
  (void)ws_size;

  hipMemsetAsync(cnt, 0, (size_t)M * 4, stream);
  prep_w_k<<<256, 256, 0, stream>>>(Ws0, Wn0, Ws1, Wn1, T0s, T0n, T1s, T1n);
  log1p_cast_k<<<4096, 256, 0, stream>>>(x, h0, N0 * 128 / 4);

  // fused CSR build (both layers)
  int B0 = (E0 / 4 + 255) / 256;  // blocks for edge list 0 (4 edges/thread)
  int B1 = (E1 / 4 + 255) / 256;
  count2_k<<<B0 + B1, 256, 0, stream>>>(dst0, E0, dst1, E1, cnt, N1, B0);
  int P = (M + 255) / 256;
  scan_block_sums_k<<<P, 256, 0, stream>>>(cnt, M, part);
  scan_partials_k<<<1, 256, 0, stream>>>(part, P);
  scan_final_k<<<P, 256, 0, stream>>>(cnt, M, part, off, cur);
  fill2_k<<<B0 + B1, 256, 0, stream>>>(src0, dst0, E0, src1, dst1, E1, cur, N1, B0, ss);

  // layer 0
  aggregate_k<2, 8><<<(N1 + 3) / 4, 256, 0, stream>>>(h0, ss, off, cnt, agg0, N1);
  layer_gemm_k<128><<<(N1 + 63) / 64, 256, 0, stream>>>(h0, agg0, T0s, T0n, b0, h1, N1);

  // layer 1
  aggregate_k<4, 8><<<(N2 + 3) / 4, 256, 0, stream>>>(h1, ss, off + N1, cnt + N1, agg1, N2);
  layer_gemm_k<256><<<(N2 + 63) / 64, 256, 0, stream>>>(h1, agg1, T1s, T1n, b1, h2, N2);

  head_k<<<(N2 + 3) / 4, 256, 0, stream>>>(h2, Wmu, bmu, Wvar, bvar, (float*)d_out, N2);
}

// Round 5
// 202.819 us; speedup vs baseline: 1.9107x; 1.3760x over previous
//
#include <hip/hip_runtime.h>
#include <math.h>

#define DEVI static __device__ __forceinline__

typedef __attribute__((ext_vector_type(8))) short s16x8;
typedef __attribute__((ext_vector_type(4))) float f32x4;

constexpr int CH = 4096;  // edges per partition block in CSR build

DEVI float bf2f(unsigned short u) {
  union { unsigned int i; float f; } v; v.i = ((unsigned int)u) << 16; return v.f;
}
DEVI unsigned short f2bf(float f) {
  union { float f; unsigned int i; } v; v.f = f;
  return (unsigned short)((v.i + 0x7fffu + ((v.i >> 16) & 1u)) >> 16);
}

// fast log1p for x in [0,1): 1+x in [1,2), no cancellation; hw log2 + scale.
DEVI float fast_log1p(float x) {
  float t = x + 1.0f;
  float l;
  asm("v_log_f32 %0, %1" : "=v"(l) : "v"(t));
  return l * 0.6931471805599453f;
}

// ---------------- h0 = bf16(log1p(x)), vectorized ----------------
__global__ void log1p_cast_k(const float* __restrict__ x, unsigned short* __restrict__ h0, int n4) {
  int stride = gridDim.x * blockDim.x;
  for (int i = blockIdx.x * blockDim.x + threadIdx.x; i < n4; i += stride) {
    float4 v = ((const float4*)x)[i];
    ushort4 o;
    o.x = f2bf(fast_log1p(v.x)); o.y = f2bf(fast_log1p(v.y));
    o.z = f2bf(fast_log1p(v.z)); o.w = f2bf(fast_log1p(v.w));
    ((ushort4*)h0)[i] = o;
  }
}

// ---------------- weight prep: W[K][256] f32 -> Wt[256][K] bf16 ----------------
__global__ void prep_w_k(const float* __restrict__ Ws0, const float* __restrict__ Wn0,
                         const float* __restrict__ Ws1, const float* __restrict__ Wn1,
                         unsigned short* __restrict__ T0s, unsigned short* __restrict__ T0n,
                         unsigned short* __restrict__ T1s, unsigned short* __restrict__ T1n) {
  int i = blockIdx.x * 256 + threadIdx.x;
  if (i < 32768) {  // [256][128]
    int h = i >> 7, k = i & 127;
    T0s[i] = f2bf(Ws0[k * 256 + h]);
    T0n[i] = f2bf(Wn0[k * 256 + h]);
  }
  if (i < 65536) {  // [256][256]
    int h = i >> 8, k = i & 255;
    T1s[i] = f2bf(Ws1[k * 256 + h]);
    T1n[i] = f2bf(Wn1[k * 256 + h]);
  }
}

// ================= CSR build via two-level LDS counting sort (no global atomics) =================
// Level 1a: per-block histogram over 256 coarse buckets (dst>>8), bucket-major layout.
__global__ __launch_bounds__(256) void hist2_k(const int* __restrict__ dst0, int E0,
                                               const int* __restrict__ dst1, int E1,
                                               unsigned* __restrict__ gh, int B0, int B1) {
  __shared__ unsigned h[256];
  int b = blockIdx.x;
  bool L1 = b >= B0;
  const int* dst = L1 ? dst1 : dst0;
  int E = L1 ? E1 : E0;
  int base = L1 ? b - B0 : b;
  unsigned* out = L1 ? gh + 256 * B0 : gh;
  int B = L1 ? B1 : B0;
  int t = threadIdx.x;
  h[t] = 0;
  __syncthreads();
  int e0 = base * CH, eend = min(e0 + CH, E);
  for (int i = e0 + t; i < eend; i += 256) atomicAdd(&h[((unsigned)dst[i]) >> 8], 1u);
  __syncthreads();
  out[t * B + base] = h[t];
}

__global__ void scan_block_sums_k(const unsigned* __restrict__ a, int M, unsigned* __restrict__ part) {
  __shared__ unsigned sm[256];
  int t = threadIdx.x;
  int i = blockIdx.x * 256 + t;
  sm[t] = (i < M) ? a[i] : 0u;
  __syncthreads();
  for (int o = 128; o > 0; o >>= 1) {
    if (t < o) sm[t] += sm[t + o];
    __syncthreads();
  }
  if (t == 0) part[blockIdx.x] = sm[0];
}

__global__ void scan_partials_k(unsigned* __restrict__ part, int P) {
  __shared__ unsigned sm[256];
  int t = threadIdx.x;
  unsigned v = (t < P) ? part[t] : 0u;
  sm[t] = v;
  __syncthreads();
  for (int o = 1; o < 256; o <<= 1) {
    unsigned xv = (t >= o) ? sm[t - o] : 0u;
    __syncthreads();
    sm[t] += xv;
    __syncthreads();
  }
  if (t < P) part[t] = sm[t] - v;  // exclusive
}

// in-place exclusive scan finalize
__global__ void scan_write_k(unsigned* __restrict__ a, int M, const unsigned* __restrict__ part) {
  __shared__ unsigned sm[256];
  int t = threadIdx.x;
  int i = blockIdx.x * 256 + t;
  unsigned v = (i < M) ? a[i] : 0u;
  sm[t] = v;
  __syncthreads();
  for (int o = 1; o < 256; o <<= 1) {
    unsigned xv = (t >= o) ? sm[t - o] : 0u;
    __syncthreads();
    sm[t] += xv;
    __syncthreads();
  }
  if (i < M) a[i] = part[blockIdx.x] + sm[t] - v;
}

// Level 1b: scatter (dst,src) pairs into bucket-grouped tmp using LDS cursors.
__global__ __launch_bounds__(256) void scatter2_k(const int* __restrict__ src0, const int* __restrict__ dst0, int E0,
                                                  const int* __restrict__ src1, const int* __restrict__ dst1, int E1,
                                                  const unsigned* __restrict__ gh, int B0, int B1,
                                                  uint2* __restrict__ tmp) {
  __shared__ unsigned cur[256];
  int b = blockIdx.x;
  bool L1 = b >= B0;
  const int* dst = L1 ? dst1 : dst0;
  const int* src = L1 ? src1 : src0;
  int E = L1 ? E1 : E0;
  int base = L1 ? b - B0 : b;
  const unsigned* g = L1 ? gh + 256 * B0 : gh;
  int B = L1 ? B1 : B0;
  int t = threadIdx.x;
  cur[t] = g[t * B + base];
  __syncthreads();
  int e0 = base * CH, eend = min(e0 + CH, E);
  for (int i = e0 + t; i < eend; i += 256) {
    int d = dst[i];
    unsigned p = atomicAdd(&cur[((unsigned)d) >> 8], 1u);
    tmp[p] = make_uint2((unsigned)d, (unsigned)src[i]);
  }
}

// Level 2: one block per coarse bucket -> fine sort + write off/cnt/ss. All-LDS atomics.
__global__ __launch_bounds__(256) void finalize_k(const uint2* __restrict__ tmp, const unsigned* __restrict__ gh,
                                                  int B0, int B1, int N1, int N2,
                                                  unsigned* __restrict__ off, unsigned* __restrict__ cnt,
                                                  int* __restrict__ ss, int QB0) {
  __shared__ unsigned h[256];
  __shared__ unsigned sm[256];
  int q = blockIdx.x;
  bool L1 = q >= QB0;
  int Nd = L1 ? N2 : N1;
  int qb = L1 ? q - QB0 : q;
  const unsigned* g = L1 ? gh + 256 * B0 : gh;
  int B = L1 ? B1 : B0;
  int t = threadIdx.x;
  unsigned bstart = g[qb * B];
  unsigned bend = g[(qb + 1) * B];  // qb<=195(B0)/39(B1), bucket qb+1 exists (zero-count tail buckets ok)
  unsigned nb = bend - bstart;

  h[t] = 0;
  __syncthreads();
  for (unsigned i = t; i < nb; i += 256) atomicAdd(&h[tmp[bstart + i].x & 255u], 1u);
  __syncthreads();
  // exclusive scan of h
  unsigned v = h[t];
  sm[t] = v;
  __syncthreads();
  for (int o = 1; o < 256; o <<= 1) {
    unsigned xv = (t >= o) ? sm[t - o] : 0u;
    __syncthreads();
    sm[t] += xv;
    __syncthreads();
  }
  unsigned myoff = bstart + sm[t] - v;  // absolute start of fine-dst segment
  int dl = qb * 256 + t;                // dst within layer
  if (dl < Nd) {
    int dgArr = (L1 ? N1 : 0) + dl;
    off[dgArr] = myoff;
    cnt[dgArr] = v;
  }
  __syncthreads();
  sm[t] = myoff;  // cursors
  __syncthreads();
  for (unsigned i = t; i < nb; i += 256) {
    uint2 e = tmp[bstart + i];
    unsigned p = atomicAdd(&sm[e.x & 255u], 1u);
    ss[p] = (int)e.y;
  }
}

// ---------------- mean aggregation: wave per dst node, U-deep gather pipeline ----------------
// FPL = feats per lane (F = FPL*64). off/cnt hold ABSOLUTE offsets into the shared ss buffer.
template <int FPL, int U>
__global__ __launch_bounds__(256) void aggregate_k(const unsigned short* __restrict__ hsrc,
                                                   const int* __restrict__ ss,
                                                   const unsigned* __restrict__ off,
                                                   const unsigned* __restrict__ cnt,
                                                   unsigned short* __restrict__ agg, int M) {
  const int F = FPL * 64;
  int w = threadIdx.x >> 6, l = threadIdx.x & 63;
  int d = blockIdx.x * 4 + w;
  if (d >= M) return;
  unsigned o = off[d];
  int n = (int)cnt[d];
  float acc[FPL];
#pragma unroll
  for (int f = 0; f < FPL; ++f) acc[f] = 0.f;

  int i = 0;
  for (; i + U <= n; i += U) {
    int sv[U];
#pragma unroll
    for (int u = 0; u < U; ++u) sv[u] = ss[o + i + u];
    if constexpr (FPL == 2) {
      unsigned v[U];
#pragma unroll
      for (int u = 0; u < U; ++u) v[u] = *(const unsigned*)&hsrc[(size_t)sv[u] * F + l * 2];
#pragma unroll
      for (int u = 0; u < U; ++u) {
        acc[0] += bf2f((unsigned short)(v[u] & 0xffffu));
        acc[1] += bf2f((unsigned short)(v[u] >> 16));
      }
    } else {
      uint2 v[U];
#pragma unroll
      for (int u = 0; u < U; ++u) v[u] = *(const uint2*)&hsrc[(size_t)sv[u] * F + l * 4];
#pragma unroll
      for (int u = 0; u < U; ++u) {
        acc[0] += bf2f((unsigned short)(v[u].x & 0xffffu));
        acc[1] += bf2f((unsigned short)(v[u].x >> 16));
        acc[2] += bf2f((unsigned short)(v[u].y & 0xffffu));
        acc[3] += bf2f((unsigned short)(v[u].y >> 16));
      }
    }
  }
  for (; i < n; ++i) {
    int s = ss[o + i];
    if constexpr (FPL == 2) {
      unsigned v = *(const unsigned*)&hsrc[(size_t)s * F + l * 2];
      acc[0] += bf2f((unsigned short)(v & 0xffffu));
      acc[1] += bf2f((unsigned short)(v >> 16));
    } else {
      uint2 v = *(const uint2*)&hsrc[(size_t)s * F + l * 4];
      acc[0] += bf2f((unsigned short)(v.x & 0xffffu));
      acc[1] += bf2f((unsigned short)(v.x >> 16));
      acc[2] += bf2f((unsigned short)(v.y & 0xffffu));
      acc[3] += bf2f((unsigned short)(v.y >> 16));
    }
  }

  float inv = 1.0f / (float)((n > 0) ? n : 1);
  if constexpr (FPL == 2) {
    unsigned ov = (unsigned)f2bf(acc[0] * inv) | ((unsigned)f2bf(acc[1] * inv) << 16);
    *(unsigned*)&agg[(size_t)d * F + l * 2] = ov;
  } else {
    ushort4 ov;
    ov.x = f2bf(acc[0] * inv); ov.y = f2bf(acc[1] * inv);
    ov.z = f2bf(acc[2] * inv); ov.w = f2bf(acc[3] * inv);
    *(ushort4*)&agg[(size_t)d * F + l * 4] = ov;
  }
}

// ---------------- fused layer GEMM: relu(Aself@Ws + Aagg@Wn + b) row-L2-normalized ----------------
// Tile: BM=64 rows x 256 cols, 4 waves; wave w owns cols [w*64, w*64+64).
template <int KD>
__global__ __launch_bounds__(256) void layer_gemm_k(const unsigned short* __restrict__ Aself,
                                                    const unsigned short* __restrict__ Aagg,
                                                    const unsigned short* __restrict__ WtS,
                                                    const unsigned short* __restrict__ WtN,
                                                    const float* __restrict__ bias,
                                                    unsigned short* __restrict__ Hout, int M) {
  __shared__ unsigned short At[64][40];   // pad 32->40: 2-way bank aliasing only
  __shared__ unsigned short Bt[256][40];
  __shared__ float rowsq[4][64];
  __shared__ float rowtot[64];

  int tid = threadIdx.x;
  int w = tid >> 6, l = tid & 63;
  int m0 = blockIdx.x * 64;

  f32x4 acc[4][4];
#pragma unroll
  for (int rt = 0; rt < 4; ++rt)
#pragma unroll
    for (int ct = 0; ct < 4; ++ct) acc[rt][ct] = (f32x4)(0.f);

  for (int s = 0; s < 2; ++s) {
    const unsigned short* A = s ? Aagg : Aself;
    const unsigned short* Wt = s ? WtN : WtS;
    for (int k0 = 0; k0 < KD; k0 += 32) {
      {  // stage A tile 64x32
        int r = tid >> 2, c8 = (tid & 3) << 3;
        int gr = m0 + r;
        uint4 v = make_uint4(0, 0, 0, 0);
        if (gr < M) v = *(const uint4*)&A[(size_t)gr * KD + k0 + c8];
        *(uint4*)&At[r][c8] = v;
      }
#pragma unroll
      for (int rr = 0; rr < 4; ++rr) {  // stage B tile: Wt rows 0..255, cols k0..k0+31
        int r = (tid >> 2) + (rr << 6), c8 = (tid & 3) << 3;
        uint4 v = *(const uint4*)&Wt[(size_t)r * KD + k0 + c8];
        *(uint4*)&Bt[r][c8] = v;
      }
      __syncthreads();
      s16x8 a[4], b[4];
#pragma unroll
      for (int rt = 0; rt < 4; ++rt) a[rt] = *(const s16x8*)&At[rt * 16 + (l & 15)][(l >> 4) * 8];
#pragma unroll
      for (int ct = 0; ct < 4; ++ct) b[ct] = *(const s16x8*)&Bt[w * 64 + ct * 16 + (l & 15)][(l >> 4) * 8];
#pragma unroll
      for (int rt = 0; rt < 4; ++rt)
#pragma unroll
        for (int ct = 0; ct < 4; ++ct)
          acc[rt][ct] = __builtin_amdgcn_mfma_f32_16x16x32_bf16(a[rt], b[ct], acc[rt][ct], 0, 0, 0);
      __syncthreads();
    }
  }

  // epilogue: bias + relu + partial row sumsq
  float pr[4][4];
#pragma unroll
  for (int rt = 0; rt < 4; ++rt)
#pragma unroll
    for (int j = 0; j < 4; ++j) pr[rt][j] = 0.f;
#pragma unroll
  for (int rt = 0; rt < 4; ++rt)
#pragma unroll
    for (int ct = 0; ct < 4; ++ct) {
      int c = w * 64 + ct * 16 + (l & 15);
      float bv = bias[c];
#pragma unroll
      for (int j = 0; j < 4; ++j) {
        float v = acc[rt][ct][j] + bv;
        v = fmaxf(v, 0.f);
        acc[rt][ct][j] = v;
        pr[rt][j] += v * v;
      }
    }
  // reduce across the 16 lanes sharing a row
#pragma unroll
  for (int rt = 0; rt < 4; ++rt)
#pragma unroll
    for (int j = 0; j < 4; ++j) {
      float p = pr[rt][j];
      for (int m = 1; m < 16; m <<= 1) p += __shfl_xor(p, m, 64);
      pr[rt][j] = p;
    }
  if ((l & 15) == 0) {
#pragma unroll
    for (int rt = 0; rt < 4; ++rt)
#pragma unroll
      for (int j = 0; j < 4; ++j) rowsq[w][rt * 16 + (l >> 4) * 4 + j] = pr[rt][j];
  }
  __syncthreads();
  if (tid < 64) rowtot[tid] = rowsq[0][tid] + rowsq[1][tid] + rowsq[2][tid] + rowsq[3][tid];
  __syncthreads();
#pragma unroll
  for (int rt = 0; rt < 4; ++rt) {
    int rbase = rt * 16 + (l >> 4) * 4;
#pragma unroll
    for (int j = 0; j < 4; ++j) {
      int r = rbase + j;
      int gr = m0 + r;
      if (gr < M) {
        float nrm = fmaxf(sqrtf(rowtot[r]), 1e-12f);
        float inv = 1.0f / nrm;
#pragma unroll
        for (int ct = 0; ct < 4; ++ct) {
          int c = w * 64 + ct * 16 + (l & 15);
          Hout[(size_t)gr * 256 + c] = f2bf(acc[rt][ct][j] * inv);
        }
      }
    }
  }
}

// ---------------- head: z_loc = h@Wmu+bmu ; z_scale = exp(h@Wvar+bvar)+1e-6 ----------------
__global__ __launch_bounds__(256) void head_k(const unsigned short* __restrict__ h2,
                                              const float* __restrict__ Wmu, const float* __restrict__ bmu,
                                              const float* __restrict__ Wvar, const float* __restrict__ bvar,
                                              float* __restrict__ out, int M) {
  int t = threadIdx.x;
  int j = t & 63;
  int r = blockIdx.x * 4 + (t >> 6);
  if (r >= M) return;
  bool mu = j < 32;
  const float* W = mu ? Wmu : Wvar;
  int c = j & 31;
  float acc = mu ? bmu[c] : bvar[c];
  const unsigned short* hr = &h2[(size_t)r * 256];
#pragma unroll 8
  for (int k = 0; k < 256; ++k) acc += bf2f(hr[k]) * W[k * 32 + c];
  if (mu)
    out[(size_t)r * 32 + c] = acc;
  else
    out[(size_t)M * 32 + (size_t)r * 32 + c] = expf(acc) + 1e-6f;
}

extern "C" void kernel_launch(void* const* d_in, const int* in_sizes, int n_in,
                              void* d_out, int out_size, void* d_ws, size_t ws_size,
                              hipStream_t stream) {
  const float* x    = (const float*)d_in[0];
  const float* Ws0  = (const float*)d_in[1];
  const float* Wn0  = (const float*)d_in[2];
  const float* b0   = (const float*)d_in[3];
  const float* Ws1  = (const float*)d_in[4];
  const float* Wn1  = (const float*)d_in[5];
  const float* b1   = (const float*)d_in[6];
  const float* Wmu  = (const float*)d_in[7];
  const float* bmu  = (const float*)d_in[8];
  const float* Wvar = (const float*)d_in[9];
  const float* bvar = (const float*)d_in[10];
  const int* src0   = (const int*)d_in[11];
  const int* dst0   = (const int*)d_in[12];
  const int* src1   = (const int*)d_in[13];
  const int* dst1   = (const int*)d_in[14];

  const int N0 = in_sizes[0] / 128;  // 200000
  const int E0 = in_sizes[11];       // 800000
  const int E1 = in_sizes[13];       // 160000
  const int N1 = 50000, N2 = 10000;  // n_dst0 / n_dst1 (fixed problem shape)
  const int M = N1 + N2;

  char* ws = (char*)d_ws;
  size_t o = 0;
  auto take = [&](size_t b) -> char* {
    size_t cur = (o + 255) & ~(size_t)255;
    o = cur + b;
    return ws + cur;
  };
  unsigned short* h0   = (unsigned short*)take((size_t)N0 * 128 * 2);
  unsigned short* agg0 = (unsigned short*)take((size_t)N1 * 128 * 2);
  unsigned short* h1   = (unsigned short*)take((size_t)N1 * 256 * 2);
  unsigned short* agg1 = (unsigned short*)take((size_t)N2 * 256 * 2);
  unsigned short* h2   = (unsigned short*)take((size_t)N2 * 256 * 2);
  unsigned short* T0s  = (unsigned short*)take(256 * 128 * 2);
  unsigned short* T0n  = (unsigned short*)take(256 * 128 * 2);
  unsigned short* T1s  = (unsigned short*)take(256 * 256 * 2);
  unsigned short* T1n  = (unsigned short*)take(256 * 256 * 2);

  int B0 = (E0 + CH - 1) / CH;   // 196
  int B1 = (E1 + CH - 1) / CH;   // 40
  int G  = 256 * (B0 + B1);      // gh entries
  int QB0 = (N1 + 255) / 256;    // 196
  int QB1 = (N2 + 255) / 256;    // 40

  unsigned* gh   = (unsigned*)take((size_t)G * 4);
  unsigned* off  = (unsigned*)take((size_t)M * 4);   // absolute offsets into ss
  unsigned* cnt  = (unsigned*)take((size_t)M * 4);
  unsigned* part = (unsigned*)take(256 * 4);
  uint2* tmp = (uint2*)take((size_t)(E0 + E1) * 8);  // bucket-grouped (dst,src)
  int* ss = (int*)take((size_t)(E0 + E1) * 4);       // final CSR edge-src buffer
  (void)ws_size;

  prep_w_k<<<256, 256, 0, stream>>>(Ws0, Wn0, Ws1, Wn1, T0s, T0n, T1s, T1n);
  log1p_cast_k<<<4096, 256, 0, stream>>>(x, h0, N0 * 128 / 4);

  // CSR build: two-level LDS counting sort, both layers in one pass
  hist2_k<<<B0 + B1, 256, 0, stream>>>(dst0, E0, dst1, E1, gh, B0, B1);
  int P = (G + 255) / 256;  // 236
  scan_block_sums_k<<<P, 256, 0, stream>>>(gh, G, part);
  scan_partials_k<<<1, 256, 0, stream>>>(part, P);
  scan_write_k<<<P, 256, 0, stream>>>(gh, G, part);
  scatter2_k<<<B0 + B1, 256, 0, stream>>>(src0, dst0, E0, src1, dst1, E1, gh, B0, B1, tmp);
  finalize_k<<<QB0 + QB1, 256, 0, stream>>>(tmp, gh, B0, B1, N1, N2, off, cnt, ss, QB0);

  // layer 0
  aggregate_k<2, 8><<<(N1 + 3) / 4, 256, 0, stream>>>(h0, ss, off, cnt, agg0, N1);
  layer_gemm_k<128><<<(N1 + 63) / 64, 256, 0, stream>>>(h0, agg0, T0s, T0n, b0, h1, N1);

  // layer 1
  aggregate_k<4, 8><<<(N2 + 3) / 4, 256, 0, stream>>>(h1, ss, off + N1, cnt + N1, agg1, N2);
  layer_gemm_k<256><<<(N2 + 63) / 64, 256, 0, stream>>>(h1, agg1, T1s, T1n, b1, h2, N2);

  head_k<<<(N2 + 3) / 4, 256, 0, stream>>>(h2, Wmu, bmu, Wvar, bvar, (float*)d_out, N2);
}

// Round 6
// 199.502 us; speedup vs baseline: 1.9425x; 1.0166x over previous
//
#include <hip/hip_runtime.h>
#include <math.h>

#define DEVI static __device__ __forceinline__

typedef __attribute__((ext_vector_type(8))) short s16x8;
typedef __attribute__((ext_vector_type(4))) float f32x4;

constexpr int CH = 4096;  // edges per partition block in CSR build

DEVI float bf2f(unsigned short u) {
  union { unsigned int i; float f; } v; v.i = ((unsigned int)u) << 16; return v.f;
}
DEVI unsigned short f2bf(float f) {
  union { float f; unsigned int i; } v; v.f = f;
  return (unsigned short)((v.i + 0x7fffu + ((v.i >> 16) & 1u)) >> 16);
}

// fast log1p for x in [0,1): 1+x in [1,2), no cancellation; hw log2 + scale.
DEVI float fast_log1p(float x) {
  float t = x + 1.0f;
  float l;
  asm("v_log_f32 %0, %1" : "=v"(l) : "v"(t));
  return l * 0.6931471805599453f;
}

// ---------------- fused front: hist (CSR level-1a) | weight prep | log1p featurize ----------------
// blocks [0, BH): per-block LDS histogram over 256 coarse buckets (dst>>8), bucket-major out.
// blocks [BH, BH+256): W[K][256] f32 -> Wt[256][K] bf16 transpose-cast.
// blocks [BH+256, BH+256+LB): h0 = bf16(log1p(x)), grid-stride.
__global__ __launch_bounds__(256) void front_k(const float* __restrict__ x, unsigned short* __restrict__ h0, int n4, int LB,
                                               const int* __restrict__ dst0, int E0,
                                               const int* __restrict__ dst1, int E1,
                                               unsigned* __restrict__ gh, int B0, int B1,
                                               const float* __restrict__ Ws0, const float* __restrict__ Wn0,
                                               const float* __restrict__ Ws1, const float* __restrict__ Wn1,
                                               unsigned short* __restrict__ T0s, unsigned short* __restrict__ T0n,
                                               unsigned short* __restrict__ T1s, unsigned short* __restrict__ T1n) {
  __shared__ unsigned h[256];
  int b = blockIdx.x;
  int t = threadIdx.x;
  int BH = B0 + B1;
  if (b < BH) {
    bool L1 = b >= B0;
    const int* dst = L1 ? dst1 : dst0;
    int E = L1 ? E1 : E0;
    int base = L1 ? b - B0 : b;
    unsigned* out = L1 ? gh + 256 * B0 : gh;
    int B = L1 ? B1 : B0;
    h[t] = 0;
    __syncthreads();
    int e0 = base * CH, eend = min(e0 + CH, E);
    for (int i = e0 + t; i < eend; i += 256) atomicAdd(&h[((unsigned)dst[i]) >> 8], 1u);
    __syncthreads();
    out[t * B + base] = h[t];
  } else if (b < BH + 256) {
    int i = (b - BH) * 256 + t;
    if (i < 32768) {  // [256][128]
      int hh = i >> 7, k = i & 127;
      T0s[i] = f2bf(Ws0[k * 256 + hh]);
      T0n[i] = f2bf(Wn0[k * 256 + hh]);
    }
    if (i < 65536) {  // [256][256]
      int hh = i >> 8, k = i & 255;
      T1s[i] = f2bf(Ws1[k * 256 + hh]);
      T1n[i] = f2bf(Wn1[k * 256 + hh]);
    }
  } else {
    int base = b - BH - 256;
    int stride = LB * 256;
    for (int i = base * 256 + t; i < n4; i += stride) {
      float4 v = ((const float4*)x)[i];
      ushort4 o;
      o.x = f2bf(fast_log1p(v.x)); o.y = f2bf(fast_log1p(v.y));
      o.z = f2bf(fast_log1p(v.z)); o.w = f2bf(fast_log1p(v.w));
      ((ushort4*)h0)[i] = o;
    }
  }
}

__global__ void scan_block_sums_k(const unsigned* __restrict__ a, int M, unsigned* __restrict__ part) {
  __shared__ unsigned sm[256];
  int t = threadIdx.x;
  int i = blockIdx.x * 256 + t;
  sm[t] = (i < M) ? a[i] : 0u;
  __syncthreads();
  for (int o = 128; o > 0; o >>= 1) {
    if (t < o) sm[t] += sm[t + o];
    __syncthreads();
  }
  if (t == 0) part[blockIdx.x] = sm[0];
}

__global__ void scan_partials_k(unsigned* __restrict__ part, int P) {
  __shared__ unsigned sm[256];
  int t = threadIdx.x;
  unsigned v = (t < P) ? part[t] : 0u;
  sm[t] = v;
  __syncthreads();
  for (int o = 1; o < 256; o <<= 1) {
    unsigned xv = (t >= o) ? sm[t - o] : 0u;
    __syncthreads();
    sm[t] += xv;
    __syncthreads();
  }
  if (t < P) part[t] = sm[t] - v;  // exclusive
}

// in-place exclusive scan finalize
__global__ void scan_write_k(unsigned* __restrict__ a, int M, const unsigned* __restrict__ part) {
  __shared__ unsigned sm[256];
  int t = threadIdx.x;
  int i = blockIdx.x * 256 + t;
  unsigned v = (i < M) ? a[i] : 0u;
  sm[t] = v;
  __syncthreads();
  for (int o = 1; o < 256; o <<= 1) {
    unsigned xv = (t >= o) ? sm[t - o] : 0u;
    __syncthreads();
    sm[t] += xv;
    __syncthreads();
  }
  if (i < M) a[i] = part[blockIdx.x] + sm[t] - v;
}

// Level 1b: scatter (dst,src) pairs into bucket-grouped tmp using LDS cursors.
__global__ __launch_bounds__(256) void scatter2_k(const int* __restrict__ src0, const int* __restrict__ dst0, int E0,
                                                  const int* __restrict__ src1, const int* __restrict__ dst1, int E1,
                                                  const unsigned* __restrict__ gh, int B0, int B1,
                                                  uint2* __restrict__ tmp) {
  __shared__ unsigned cur[256];
  int b = blockIdx.x;
  bool L1 = b >= B0;
  const int* dst = L1 ? dst1 : dst0;
  const int* src = L1 ? src1 : src0;
  int E = L1 ? E1 : E0;
  int base = L1 ? b - B0 : b;
  const unsigned* g = L1 ? gh + 256 * B0 : gh;
  int B = L1 ? B1 : B0;
  int t = threadIdx.x;
  cur[t] = g[t * B + base];
  __syncthreads();
  int e0 = base * CH, eend = min(e0 + CH, E);
  for (int i = e0 + t; i < eend; i += 256) {
    int d = dst[i];
    unsigned p = atomicAdd(&cur[((unsigned)d) >> 8], 1u);
    tmp[p] = make_uint2((unsigned)d, (unsigned)src[i]);
  }
}

// Level 2: one block per coarse bucket -> fine sort + write off/cnt/ss. All-LDS atomics.
__global__ __launch_bounds__(256) void finalize_k(const uint2* __restrict__ tmp, const unsigned* __restrict__ gh,
                                                  int B0, int B1, int N1, int N2,
                                                  unsigned* __restrict__ off, unsigned* __restrict__ cnt,
                                                  int* __restrict__ ss, int QB0) {
  __shared__ unsigned h[256];
  __shared__ unsigned sm[256];
  int q = blockIdx.x;
  bool L1 = q >= QB0;
  int Nd = L1 ? N2 : N1;
  int qb = L1 ? q - QB0 : q;
  const unsigned* g = L1 ? gh + 256 * B0 : gh;
  int B = L1 ? B1 : B0;
  int t = threadIdx.x;
  unsigned bstart = g[qb * B];
  unsigned bend = g[(qb + 1) * B];  // bucket qb+1 row exists (<=255); zero-count tail buckets ok
  unsigned nb = bend - bstart;

  h[t] = 0;
  __syncthreads();
  for (unsigned i = t; i < nb; i += 256) atomicAdd(&h[tmp[bstart + i].x & 255u], 1u);
  __syncthreads();
  // exclusive scan of h
  unsigned v = h[t];
  sm[t] = v;
  __syncthreads();
  for (int o = 1; o < 256; o <<= 1) {
    unsigned xv = (t >= o) ? sm[t - o] : 0u;
    __syncthreads();
    sm[t] += xv;
    __syncthreads();
  }
  unsigned myoff = bstart + sm[t] - v;  // absolute start of fine-dst segment
  int dl = qb * 256 + t;                // dst within layer
  if (dl < Nd) {
    int dgArr = (L1 ? N1 : 0) + dl;
    off[dgArr] = myoff;
    cnt[dgArr] = v;
  }
  __syncthreads();
  sm[t] = myoff;  // cursors
  __syncthreads();
  for (unsigned i = t; i < nb; i += 256) {
    uint2 e = tmp[bstart + i];
    unsigned p = atomicAdd(&sm[e.x & 255u], 1u);
    ss[p] = (int)e.y;
  }
}

// ---------------- mean aggregation: wave per dst node, U-deep gather pipeline ----------------
// FPL = feats per lane (F = FPL*64). off/cnt hold ABSOLUTE offsets into the shared ss buffer.
template <int FPL, int U>
__global__ __launch_bounds__(256) void aggregate_k(const unsigned short* __restrict__ hsrc,
                                                   const int* __restrict__ ss,
                                                   const unsigned* __restrict__ off,
                                                   const unsigned* __restrict__ cnt,
                                                   unsigned short* __restrict__ agg, int M) {
  const int F = FPL * 64;
  int w = threadIdx.x >> 6, l = threadIdx.x & 63;
  int d = blockIdx.x * 4 + w;
  if (d >= M) return;
  unsigned o = off[d];
  int n = (int)cnt[d];
  float acc[FPL];
#pragma unroll
  for (int f = 0; f < FPL; ++f) acc[f] = 0.f;

  int i = 0;
  for (; i + U <= n; i += U) {
    int sv[U];
#pragma unroll
    for (int u = 0; u < U; ++u) sv[u] = ss[o + i + u];
    if constexpr (FPL == 2) {
      unsigned v[U];
#pragma unroll
      for (int u = 0; u < U; ++u) v[u] = *(const unsigned*)&hsrc[(size_t)sv[u] * F + l * 2];
#pragma unroll
      for (int u = 0; u < U; ++u) {
        acc[0] += bf2f((unsigned short)(v[u] & 0xffffu));
        acc[1] += bf2f((unsigned short)(v[u] >> 16));
      }
    } else {
      uint2 v[U];
#pragma unroll
      for (int u = 0; u < U; ++u) v[u] = *(const uint2*)&hsrc[(size_t)sv[u] * F + l * 4];
#pragma unroll
      for (int u = 0; u < U; ++u) {
        acc[0] += bf2f((unsigned short)(v[u].x & 0xffffu));
        acc[1] += bf2f((unsigned short)(v[u].x >> 16));
        acc[2] += bf2f((unsigned short)(v[u].y & 0xffffu));
        acc[3] += bf2f((unsigned short)(v[u].y >> 16));
      }
    }
  }
  for (; i < n; ++i) {
    int s = ss[o + i];
    if constexpr (FPL == 2) {
      unsigned v = *(const unsigned*)&hsrc[(size_t)s * F + l * 2];
      acc[0] += bf2f((unsigned short)(v & 0xffffu));
      acc[1] += bf2f((unsigned short)(v >> 16));
    } else {
      uint2 v = *(const uint2*)&hsrc[(size_t)s * F + l * 4];
      acc[0] += bf2f((unsigned short)(v.x & 0xffffu));
      acc[1] += bf2f((unsigned short)(v.x >> 16));
      acc[2] += bf2f((unsigned short)(v.y & 0xffffu));
      acc[3] += bf2f((unsigned short)(v.y >> 16));
    }
  }

  float inv = 1.0f / (float)((n > 0) ? n : 1);
  if constexpr (FPL == 2) {
    unsigned ov = (unsigned)f2bf(acc[0] * inv) | ((unsigned)f2bf(acc[1] * inv) << 16);
    *(unsigned*)&agg[(size_t)d * F + l * 2] = ov;
  } else {
    ushort4 ov;
    ov.x = f2bf(acc[0] * inv); ov.y = f2bf(acc[1] * inv);
    ov.z = f2bf(acc[2] * inv); ov.w = f2bf(acc[3] * inv);
    *(ushort4*)&agg[(size_t)d * F + l * 4] = ov;
  }
}

// ---------------- fused layer GEMM: relu(Aself@Ws + Aagg@Wn + b) row-L2-normalized ----------------
// Tile: BM=128 rows x 256 cols, 8 waves (2 row-groups x 4 col-groups), 512 threads.
template <int KD>
__global__ __launch_bounds__(512) void layer_gemm_k(const unsigned short* __restrict__ Aself,
                                                    const unsigned short* __restrict__ Aagg,
                                                    const unsigned short* __restrict__ WtS,
                                                    const unsigned short* __restrict__ WtN,
                                                    const float* __restrict__ bias,
                                                    unsigned short* __restrict__ Hout, int M) {
  __shared__ unsigned short At[128][40];   // pad 32->40: 2-way bank aliasing only
  __shared__ unsigned short Bt[256][40];
  __shared__ float rowsq[4][128];
  __shared__ float rowtot[128];

  int tid = threadIdx.x;
  int w = tid >> 6, l = tid & 63;
  int wr = w >> 2, wc = w & 3;
  int m0 = blockIdx.x * 128;

  f32x4 acc[4][4];
#pragma unroll
  for (int rt = 0; rt < 4; ++rt)
#pragma unroll
    for (int ct = 0; ct < 4; ++ct) acc[rt][ct] = (f32x4)(0.f);

  for (int s = 0; s < 2; ++s) {
    const unsigned short* A = s ? Aagg : Aself;
    const unsigned short* Wt = s ? WtN : WtS;
    for (int k0 = 0; k0 < KD; k0 += 32) {
      {  // stage A tile 128x32: one uint4/thread
        int r = tid >> 2, c8 = (tid & 3) << 3;
        int gr = m0 + r;
        uint4 v = make_uint4(0, 0, 0, 0);
        if (gr < M) v = *(const uint4*)&A[(size_t)gr * KD + k0 + c8];
        *(uint4*)&At[r][c8] = v;
      }
#pragma unroll
      for (int rr = 0; rr < 2; ++rr) {  // stage B tile 256x32: two uint4/thread
        int r = (tid >> 2) + (rr << 7), c8 = (tid & 3) << 3;
        uint4 v = *(const uint4*)&Wt[(size_t)r * KD + k0 + c8];
        *(uint4*)&Bt[r][c8] = v;
      }
      __syncthreads();
      s16x8 a[4], b[4];
#pragma unroll
      for (int rt = 0; rt < 4; ++rt) a[rt] = *(const s16x8*)&At[wr * 64 + rt * 16 + (l & 15)][(l >> 4) * 8];
#pragma unroll
      for (int ct = 0; ct < 4; ++ct) b[ct] = *(const s16x8*)&Bt[wc * 64 + ct * 16 + (l & 15)][(l >> 4) * 8];
#pragma unroll
      for (int rt = 0; rt < 4; ++rt)
#pragma unroll
        for (int ct = 0; ct < 4; ++ct)
          acc[rt][ct] = __builtin_amdgcn_mfma_f32_16x16x32_bf16(a[rt], b[ct], acc[rt][ct], 0, 0, 0);
      __syncthreads();
    }
  }

  // epilogue: bias + relu + partial row sumsq
  float pr[4][4];
#pragma unroll
  for (int rt = 0; rt < 4; ++rt)
#pragma unroll
    for (int j = 0; j < 4; ++j) pr[rt][j] = 0.f;
#pragma unroll
  for (int rt = 0; rt < 4; ++rt)
#pragma unroll
    for (int ct = 0; ct < 4; ++ct) {
      int c = wc * 64 + ct * 16 + (l & 15);
      float bv = bias[c];
#pragma unroll
      for (int j = 0; j < 4; ++j) {
        float v = acc[rt][ct][j] + bv;
        v = fmaxf(v, 0.f);
        acc[rt][ct][j] = v;
        pr[rt][j] += v * v;
      }
    }
  // reduce across the 16 lanes sharing a row
#pragma unroll
  for (int rt = 0; rt < 4; ++rt)
#pragma unroll
    for (int j = 0; j < 4; ++j) {
      float p = pr[rt][j];
      for (int m = 1; m < 16; m <<= 1) p += __shfl_xor(p, m, 64);
      pr[rt][j] = p;
    }
  if ((l & 15) == 0) {
#pragma unroll
    for (int rt = 0; rt < 4; ++rt)
#pragma unroll
      for (int j = 0; j < 4; ++j) rowsq[wc][wr * 64 + rt * 16 + (l >> 4) * 4 + j] = pr[rt][j];
  }
  __syncthreads();
  if (tid < 128) rowtot[tid] = rowsq[0][tid] + rowsq[1][tid] + rowsq[2][tid] + rowsq[3][tid];
  __syncthreads();
#pragma unroll
  for (int rt = 0; rt < 4; ++rt) {
    int rbase = wr * 64 + rt * 16 + (l >> 4) * 4;
#pragma unroll
    for (int j = 0; j < 4; ++j) {
      int r = rbase + j;
      int gr = m0 + r;
      if (gr < M) {
        float nrm = fmaxf(sqrtf(rowtot[r]), 1e-12f);
        float inv = 1.0f / nrm;
#pragma unroll
        for (int ct = 0; ct < 4; ++ct) {
          int c = wc * 64 + ct * 16 + (l & 15);
          Hout[(size_t)gr * 256 + c] = f2bf(acc[rt][ct][j] * inv);
        }
      }
    }
  }
}

// ---------------- head: z_loc = h@Wmu+bmu ; z_scale = exp(h@Wvar+bvar)+1e-6 ----------------
__global__ __launch_bounds__(256) void head_k(const unsigned short* __restrict__ h2,
                                              const float* __restrict__ Wmu, const float* __restrict__ bmu,
                                              const float* __restrict__ Wvar, const float* __restrict__ bvar,
                                              float* __restrict__ out, int M) {
  int t = threadIdx.x;
  int j = t & 63;
  int r = blockIdx.x * 4 + (t >> 6);
  if (r >= M) return;
  bool mu = j < 32;
  const float* W = mu ? Wmu : Wvar;
  int c = j & 31;
  float acc = mu ? bmu[c] : bvar[c];
  const unsigned short* hr = &h2[(size_t)r * 256];
#pragma unroll 8
  for (int k = 0; k < 256; ++k) acc += bf2f(hr[k]) * W[k * 32 + c];
  if (mu)
    out[(size_t)r * 32 + c] = acc;
  else
    out[(size_t)M * 32 + (size_t)r * 32 + c] = expf(acc) + 1e-6f;
}

extern "C" void kernel_launch(void* const* d_in, const int* in_sizes, int n_in,
                              void* d_out, int out_size, void* d_ws, size_t ws_size,
                              hipStream_t stream) {
  const float* x    = (const float*)d_in[0];
  const float* Ws0  = (const float*)d_in[1];
  const float* Wn0  = (const float*)d_in[2];
  const float* b0   = (const float*)d_in[3];
  const float* Ws1  = (const float*)d_in[4];
  const float* Wn1  = (const float*)d_in[5];
  const float* b1   = (const float*)d_in[6];
  const float* Wmu  = (const float*)d_in[7];
  const float* bmu  = (const float*)d_in[8];
  const float* Wvar = (const float*)d_in[9];
  const float* bvar = (const float*)d_in[10];
  const int* src0   = (const int*)d_in[11];
  const int* dst0   = (const int*)d_in[12];
  const int* src1   = (const int*)d_in[13];
  const int* dst1   = (const int*)d_in[14];

  const int N0 = in_sizes[0] / 128;  // 200000
  const int E0 = in_sizes[11];       // 800000
  const int E1 = in_sizes[13];       // 160000
  const int N1 = 50000, N2 = 10000;  // n_dst0 / n_dst1 (fixed problem shape)
  const int M = N1 + N2;

  char* ws = (char*)d_ws;
  size_t o = 0;
  auto take = [&](size_t b) -> char* {
    size_t cur = (o + 255) & ~(size_t)255;
    o = cur + b;
    return ws + cur;
  };
  unsigned short* h0   = (unsigned short*)take((size_t)N0 * 128 * 2);
  unsigned short* agg0 = (unsigned short*)take((size_t)N1 * 128 * 2);
  unsigned short* h1   = (unsigned short*)take((size_t)N1 * 256 * 2);
  unsigned short* agg1 = (unsigned short*)take((size_t)N2 * 256 * 2);
  unsigned short* h2   = (unsigned short*)take((size_t)N2 * 256 * 2);
  unsigned short* T0s  = (unsigned short*)take(256 * 128 * 2);
  unsigned short* T0n  = (unsigned short*)take(256 * 128 * 2);
  unsigned short* T1s  = (unsigned short*)take(256 * 256 * 2);
  unsigned short* T1n  = (unsigned short*)take(256 * 256 * 2);

  int B0 = (E0 + CH - 1) / CH;   // 196
  int B1 = (E1 + CH - 1) / CH;   // 40
  int G  = 256 * (B0 + B1);      // gh entries
  int QB0 = (N1 + 255) / 256;    // 196
  int QB1 = (N2 + 255) / 256;    // 40

  unsigned* gh   = (unsigned*)take((size_t)G * 4);
  unsigned* off  = (unsigned*)take((size_t)M * 4);   // absolute offsets into ss
  unsigned* cnt  = (unsigned*)take((size_t)M * 4);
  unsigned* part = (unsigned*)take(256 * 4);
  uint2* tmp = (uint2*)take((size_t)(E0 + E1) * 8);  // bucket-grouped (dst,src)
  int* ss = (int*)take((size_t)(E0 + E1) * 4);       // final CSR edge-src buffer
  (void)ws_size;

  // fused front: hist + weight prep + log1p (independent phases, one launch)
  const int LB = 2048;
  front_k<<<B0 + B1 + 256 + LB, 256, 0, stream>>>(x, h0, N0 * 128 / 4, LB,
                                                  dst0, E0, dst1, E1, gh, B0, B1,
                                                  Ws0, Wn0, Ws1, Wn1, T0s, T0n, T1s, T1n);

  // CSR: scan + scatter + finalize
  int P = (G + 255) / 256;  // 236
  scan_block_sums_k<<<P, 256, 0, stream>>>(gh, G, part);
  scan_partials_k<<<1, 256, 0, stream>>>(part, P);
  scan_write_k<<<P, 256, 0, stream>>>(gh, G, part);
  scatter2_k<<<B0 + B1, 256, 0, stream>>>(src0, dst0, E0, src1, dst1, E1, gh, B0, B1, tmp);
  finalize_k<<<QB0 + QB1, 256, 0, stream>>>(tmp, gh, B0, B1, N1, N2, off, cnt, ss, QB0);

  // layer 0
  aggregate_k<2, 8><<<(N1 + 3) / 4, 256, 0, stream>>>(h0, ss, off, cnt, agg0, N1);
  layer_gemm_k<128><<<(N1 + 127) / 128, 512, 0, stream>>>(h0, agg0, T0s, T0n, b0, h1, N1);

  // layer 1
  aggregate_k<4, 8><<<(N2 + 3) / 4, 256, 0, stream>>>(h1, ss, off + N1, cnt + N1, agg1, N2);
  layer_gemm_k<256><<<(N2 + 127) / 128, 512, 0, stream>>>(h1, agg1, T1s, T1n, b1, h2, N2);

  head_k<<<(N2 + 3) / 4, 256, 0, stream>>>(h2, Wmu, bmu, Wvar, bvar, (float*)d_out, N2);
}